// Round 9
// baseline (463.019 us; speedup 1.0000x reference)
//
#include <hip/hip_runtime.h>
#include <math.h>

#define S_TOT 8192
#define DD 256
#define NHEAD 8
#define HDSZ 32
#define ATT_SCALE 0.17677669529663687f
#define ATT_SCALE_LOG2E 0.25506601f   // ATT_SCALE * log2(e)

typedef short short8 __attribute__((ext_vector_type(8)));
typedef short short4v __attribute__((ext_vector_type(4)));
typedef float f32x4 __attribute__((ext_vector_type(4)));
typedef unsigned short ushort;

// wbuf offsets (ushort elements)
#define OFF_PROJ 0
#define OFF_WQ0  393216
#define OFF_WK0  458752
#define OFF_WV0  524288
#define OFF_WO0  589824
#define OFF_W10  655360
#define OFF_W20  917504
#define OFF_WK1  1179648
#define OFF_WV1  1245184
#define OFF_WQ1  1310720
#define OFF_WO1  1376256
#define OFF_W11  1441792
#define OFF_W21  1703936
#define WBUF_TOT 1966080

__device__ inline ushort f2bf(float f) {
    union { float f; unsigned u; } c; c.f = f;
    unsigned u = c.u;
    u += 0x7fffu + ((u >> 16) & 1u);          // RNE
    return (ushort)(u >> 16);
}
__device__ inline float bf2f(ushort u) {
    union { unsigned u; float f; } c; c.u = ((unsigned)u) << 16;
    return c.f;
}
__device__ inline float gelu_exact(float v) {
    return 0.5f * v * (1.0f + erff(v * 0.7071067811865475f));
}
__device__ inline unsigned cvtpk_bf16(float a, float b) {
    unsigned r;
    asm("v_cvt_pk_bf16_f32 %0, %1, %2" : "=v"(r) : "v"(a), "v"(b));
    return r;   // low16 = bf16(a), high16 = bf16(b), RNE
}
__device__ inline short8 cat44(short4v a, short4v b) {
    return __builtin_shufflevector(a, b, 0, 1, 2, 3, 4, 5, 6, 7);
}
__device__ inline float block_sum256(float v, float* red) {
    #pragma unroll
    for (int off = 32; off > 0; off >>= 1) v += __shfl_down(v, off, 64);
    const int wid = threadIdx.x >> 6, lane = threadIdx.x & 63;
    if (lane == 0) red[wid] = v;
    __syncthreads();
    const float s = red[0] + red[1] + red[2] + red[3];
    __syncthreads();
    return s;
}

// ============ setup: weight transposes + bias concat + x->bf16 + cls ============
__global__ __launch_bounds__(256)
void setup_kernel(const float* __restrict__ x, const float* __restrict__ proj_w,
                  const float* __restrict__ Wq, const float* __restrict__ Wk,
                  const float* __restrict__ Wv, const float* __restrict__ Wo,
                  const float* __restrict__ W1, const float* __restrict__ W2,
                  const float* __restrict__ bq, const float* __restrict__ bk,
                  const float* __restrict__ bv, const float* __restrict__ cls_tok,
                  ushort* __restrict__ wbuf, float* __restrict__ bqkv0,
                  float* __restrict__ bkv1, ushort* __restrict__ xbf,
                  float* __restrict__ h)
{
    const int b = blockIdx.x;
    const int t = threadIdx.x;
    if (b >= 482) {
        if (b == 6626) { h[t] = cls_tok[t]; return; }   // cls (tab[0]==0)
        const int i = (b - 482) * 256 + t;
        const int n8 = 8191 * 1536 / 8;
        if (i >= n8) return;
        const float4 a0 = *(const float4*)(x + (size_t)i * 8);
        const float4 a1 = *(const float4*)(x + (size_t)i * 8 + 4);
        ushort tmp[8] = { f2bf(a0.x), f2bf(a0.y), f2bf(a0.z), f2bf(a0.w),
                          f2bf(a1.x), f2bf(a1.y), f2bf(a1.z), f2bf(a1.w) };
        *(uint4*)(xbf + (size_t)i * 8) = *(const uint4*)tmp;
        return;
    }
    if (b >= 480) {
        if (b == 480) {
            for (int i = t; i < 768; i += 256)
                bqkv0[i] = (i < 256) ? bq[i] : ((i < 512) ? bk[i - 256] : bv[i - 512]);
        } else {
            for (int i = t; i < 512; i += 256)
                bkv1[i] = (i < 256) ? bk[256 + i] : bv[i];
        }
        return;
    }
    const float* src; ushort* dst; int R, C, t0;
    if (b < 96)       { src = proj_w;        dst = wbuf + OFF_PROJ; R = 1536; C = 256;  t0 = 0;   }
    else if (b < 112) { src = Wq;            dst = wbuf + OFF_WQ0;  R = 256;  C = 256;  t0 = 96;  }
    else if (b < 128) { src = Wk;            dst = wbuf + OFF_WK0;  R = 256;  C = 256;  t0 = 112; }
    else if (b < 144) { src = Wv;            dst = wbuf + OFF_WV0;  R = 256;  C = 256;  t0 = 128; }
    else if (b < 160) { src = Wo;            dst = wbuf + OFF_WO0;  R = 256;  C = 256;  t0 = 144; }
    else if (b < 224) { src = W1;            dst = wbuf + OFF_W10;  R = 256;  C = 1024; t0 = 160; }
    else if (b < 288) { src = W2;            dst = wbuf + OFF_W20;  R = 1024; C = 256;  t0 = 224; }
    else if (b < 304) { src = Wk + 65536;    dst = wbuf + OFF_WK1;  R = 256;  C = 256;  t0 = 288; }
    else if (b < 320) { src = Wv + 65536;    dst = wbuf + OFF_WV1;  R = 256;  C = 256;  t0 = 304; }
    else if (b < 336) { src = Wq + 65536;    dst = wbuf + OFF_WQ1;  R = 256;  C = 256;  t0 = 320; }
    else if (b < 352) { src = Wo + 65536;    dst = wbuf + OFF_WO1;  R = 256;  C = 256;  t0 = 336; }
    else if (b < 416) { src = W1 + 262144;   dst = wbuf + OFF_W11;  R = 256;  C = 1024; t0 = 352; }
    else              { src = W2 + 262144;   dst = wbuf + OFF_W21;  R = 1024; C = 256;  t0 = 416; }
    const int lt = b - t0;
    const int tC = C >> 6;
    const int tr = lt / tC, tc = lt % tC;
    __shared__ ushort tile[64][68];
    const int col = t & 63;
    const int r4  = t >> 6;
    #pragma unroll
    for (int i = 0; i < 16; ++i) {
        const int row = i * 4 + r4;
        tile[row][col] = f2bf(src[(size_t)(tr * 64 + row) * C + tc * 64 + col]);
    }
    __syncthreads();
    #pragma unroll
    for (int i = 0; i < 16; ++i) {
        const int n = i * 4 + r4;
        dst[(size_t)(tc * 64 + n) * R + tr * 64 + col] = tile[col][n];
    }
}

// ============ LayerNorm over D=256: one ROW PER WAVE, no barriers ============
__global__ __launch_bounds__(256)
void ln_kernel(const float* __restrict__ in, const float* __restrict__ g,
               const float* __restrict__ b, ushort* __restrict__ outp)
{
    const int row  = blockIdx.x * 4 + (threadIdx.x >> 6);
    const int lane = threadIdx.x & 63;
    const float4 xv = *(const float4*)(in + (size_t)row * DD + lane * 4);
    float s = (xv.x + xv.y) + (xv.z + xv.w);
    #pragma unroll
    for (int off = 32; off > 0; off >>= 1) s += __shfl_xor(s, off, 64);
    const float mu = s * (1.0f / 256.0f);
    const float dx = xv.x - mu, dy = xv.y - mu, dz = xv.z - mu, dw = xv.w - mu;
    float v2 = (dx * dx + dy * dy) + (dz * dz + dw * dw);
    #pragma unroll
    for (int off = 32; off > 0; off >>= 1) v2 += __shfl_xor(v2, off, 64);
    const float rs = rsqrtf(v2 * (1.0f / 256.0f) + 1e-5f);
    const float4 gv = *(const float4*)(g + lane * 4);
    const float4 bv = *(const float4*)(b + lane * 4);
    uint2 w;
    w.x = cvtpk_bf16(dx * rs * gv.x + bv.x, dy * rs * gv.y + bv.y);
    w.y = cvtpk_bf16(dz * rs * gv.z + bv.z, dw * rs * gv.w + bv.w);
    *(uint2*)(outp + (size_t)row * DD + lane * 4) = w;
}

// ============ gemm4: BM=64 x BN=64, BK=64, XCD-swizzled 1-D grid ============
// C = [C +] act(A @ Bt^T + bias) [+ pos].  A bf16 MxK, Bt bf16 NxK.
// flags: 1 = acc into fp32 C, 2 = GELU, 4 = bf16 out, 8 = pos-embed,
//        16 = scale cols<256 by ATT_SCALE_LOG2E (pre-scaled Q for attn).
// T3+T4 pipeline: 3 LDS buffers, depth-2 global_load_lds prefetch, counted
// s_waitcnt vmcnt(4) + raw s_barrier, ONE barrier per k-step.
// (BN=128 variant measured +10us net across the wide gemms -- retired.)
template <int BN>
__global__ __launch_bounds__(256)
void gemm4_kernel(const ushort* __restrict__ A, const ushort* __restrict__ Bt,
                  const float* __restrict__ bias, void* __restrict__ Cv,
                  int M, int N, int K, int flags, const int* __restrict__ coords)
{
    __shared__ ushort As[3][64][64];
    __shared__ ushort Bs[3][BN][64];
    constexpr int NT = BN / 32;                // MFMA n-tiles per wave
    const int nx  = N / BN;
    const int ny8 = gridDim.x / (8 * nx);      // m-slabs per XCD (=16)
    const int b   = blockIdx.x;
    const int c8  = b & 7;
    const int j   = b >> 3;
    const int m0  = (c8 * ny8 + j / nx) * 64;
    const int n0  = (j % nx) * BN;

    const int tid  = threadIdx.x;
    const int wave = tid >> 6;
    const int lane = tid & 63;
    const int lrow = lane & 15;
    const int quad = lane >> 4;
    const int wr = (wave >> 1) * 32;           // {0,32}
    const int wc = (wave & 1) * (BN / 2);      // {0,BN/2}

    float* Cf  = (float*)Cv;
    ushort* Cb = (ushort*)Cv;

    f32x4 acc[2][NT];
    #pragma unroll
    for (int mt = 0; mt < 2; ++mt)
        #pragma unroll
        for (int nt = 0; nt < NT; ++nt)
            acc[mt][nt] = (f32x4){0.f, 0.f, 0.f, 0.f};

    const int srow = tid >> 3;                 // 0..31 row within chunk
    const int scol = (tid & 7) * 16;           // byte col 0..112

    #define STAGE(BUF, KK)                                                        \
    do {                                                                          \
        _Pragma("unroll")                                                         \
        for (int c = 0; c < 2; ++c) {                                             \
            const int row = c * 32 + srow;                                        \
            const int sb  = scol ^ ((row & 7) << 4);                              \
            const ushort* srcp = A + (size_t)(m0 + row) * K + (KK) + (sb >> 1);   \
            __builtin_amdgcn_global_load_lds(                                     \
                (const __attribute__((address_space(1))) void*)srcp,              \
                (__attribute__((address_space(3))) void*)&As[BUF][c * 32 + wave * 8][0], \
                16, 0, 0);                                                        \
        }                                                                         \
        _Pragma("unroll")                                                         \
        for (int c = 0; c < BN / 32; ++c) {                                       \
            const int row = c * 32 + srow;                                        \
            const int sb  = scol ^ ((row & 7) << 4);                              \
            const ushort* srcp = Bt + (size_t)(n0 + row) * K + (KK) + (sb >> 1);  \
            __builtin_amdgcn_global_load_lds(                                     \
                (const __attribute__((address_space(1))) void*)srcp,              \
                (__attribute__((address_space(3))) void*)&Bs[BUF][c * 32 + wave * 8][0], \
                16, 0, 0);                                                        \
        }                                                                         \
    } while (0)

    #define COMPUTE(BUF)                                                          \
    do {                                                                          \
        _Pragma("unroll")                                                         \
        for (int ks = 0; ks < 2; ++ks) {                                          \
            short8 af[2], bfr[NT];                                                \
            _Pragma("unroll")                                                     \
            for (int mt = 0; mt < 2; ++mt) {                                      \
                const int row = wr + mt * 16 + lrow;                              \
                const int cb  = (ks * 64 + quad * 16) ^ ((row & 7) << 4);         \
                af[mt] = *(const short8*)((const char*)&As[BUF][row][0] + cb);    \
            }                                                                     \
            _Pragma("unroll")                                                     \
            for (int nt = 0; nt < NT; ++nt) {                                     \
                const int row = wc + nt * 16 + lrow;                              \
                const int cb  = (ks * 64 + quad * 16) ^ ((row & 7) << 4);         \
                bfr[nt] = *(const short8*)((const char*)&Bs[BUF][row][0] + cb);   \
            }                                                                     \
            _Pragma("unroll")                                                     \
            for (int mt = 0; mt < 2; ++mt)                                        \
                _Pragma("unroll")                                                 \
                for (int nt = 0; nt < NT; ++nt)                                   \
                    acc[mt][nt] = __builtin_amdgcn_mfma_f32_16x16x32_bf16(        \
                                      af[mt], bfr[nt], acc[mt][nt], 0, 0, 0);     \
        }                                                                         \
    } while (0)

    #define WAIT_BAR_N()                                                          \
    do {                                                                          \
        if constexpr (BN == 64) { asm volatile("s_waitcnt vmcnt(4)" ::: "memory"); } \
        else                    { asm volatile("s_waitcnt vmcnt(6)" ::: "memory"); } \
        __builtin_amdgcn_sched_barrier(0);                                        \
        __builtin_amdgcn_s_barrier();                                             \
        __builtin_amdgcn_sched_barrier(0);                                        \
    } while (0)

    #define WAIT_BAR_0()                                                          \
    do {                                                                          \
        asm volatile("s_waitcnt vmcnt(0)" ::: "memory");                          \
        __builtin_amdgcn_sched_barrier(0);                                        \
        __builtin_amdgcn_s_barrier();                                             \
        __builtin_amdgcn_sched_barrier(0);                                        \
    } while (0)

    const int ktiles = K >> 6;                 // >= 4 for all call sites
    STAGE(0, 0);
    STAGE(1, 64);
    int bt = 0;
    for (int t = 0; t < ktiles - 2; ++t) {
        WAIT_BAR_N();                          // tile t landed; t+1 in flight
        const int nb = (bt + 2 >= 3) ? bt - 1 : bt + 2;
        STAGE(nb, (t + 2) * 64);               // in flight: t+1, t+2
        COMPUTE(bt);
        bt = (bt + 1 == 3) ? 0 : bt + 1;
    }
    WAIT_BAR_N();                              // tile ktiles-2 landed
    COMPUTE(bt);
    bt = (bt + 1 == 3) ? 0 : bt + 1;
    WAIT_BAR_0();                              // tile ktiles-1 landed
    COMPUTE(bt);
    #undef STAGE
    #undef COMPUTE
    #undef WAIT_BAR_N
    #undef WAIT_BAR_0

    #pragma unroll
    for (int mt = 0; mt < 2; ++mt) {
        #pragma unroll
        for (int rg = 0; rg < 4; ++rg) {
            const int r = m0 + wr + mt * 16 + quad * 4 + rg;
            if (r >= M) continue;
            #pragma unroll
            for (int nt = 0; nt < NT; ++nt) {
                const int c = n0 + wc + nt * 16 + lrow;
                float vv = acc[mt][nt][rg] + bias[c];
                if (flags & 8) {   // pos-embed for token r (output = h row r+1)
                    const int cg = coords[2 * r + ((c < 128) ? 1 : 0)] >> 8;
                    // omega = 10000^(-(c&63)/64) = exp2(-(c&63)*log2(1e4)/64)
                    const float omega = exp2f((float)(c & 63) * -0.2076205059304703f);
                    const float o = (float)cg * omega;
                    vv += ((c & 64) == 0) ? __sinf(o) : __cosf(o);
                }
                if (flags & 16) { if (c < 256) vv *= ATT_SCALE_LOG2E; }
                if (flags & 2) vv = gelu_exact(vv);
                if (flags & 4) {
                    Cb[(size_t)r * N + c] = f2bf(vv);
                } else {
                    if (flags & 1) vv += Cf[(size_t)r * N + c];
                    Cf[(size_t)r * N + c] = vv;
                }
            }
        }
    }
}

// ============ MFMA dilated attention (bf16, no-max softmax) ============
// R7-verified version (58.5us): 4 waves/block, swapped QK^T (sc=mfma(K,Q))
// puts P lane-local; PV A-fragment = cvt_pk words in registers (zero P LDS
// traffic); B-fragment = ds_read_b64 pair from rotated Vt. Kb/Vt double-
// buffered, one barrier per k-step, 1-step register K/V prefetch.
// (R8 single-wave variant spilled to scratch -> 130MB/dispatch HBM writes,
// 2x slower -- retired.)
__global__ __launch_bounds__(256)
void attn_mfma_kernel(const ushort* __restrict__ q, const ushort* __restrict__ k,
                      const ushort* __restrict__ v, float* __restrict__ bo5,
                      float* __restrict__ lse5, int qs)
{
    __shared__ ushort Kb[2][64][40];
    __shared__ ushort Vt[2][32][72];

    const int unit = blockIdx.x;
    const int segu = unit >> 3;
    const int head = unit & 7;
    int b2, n;
    if (segu < 8)        { b2 = 0; n = segu; }
    else if (segu < 12)  { b2 = 1; n = segu - 8; }
    else if (segu < 14)  { b2 = 2; n = segu - 12; }
    else if (segu == 14) { b2 = 3; n = 0; }
    else                 { b2 = 4; n = 0; }
    const int w  = 1024 << b2;
    const int rr = 1 << b2;
    const int base = n * w + (head & (rr - 1));

    int kEnd = (S_TOT - base + rr - 1) >> b2;
    if (kEnd > 1024) kEnd = 1024;
    if (blockIdx.y * 128 >= kEnd) return;

    const int tid  = threadIdx.x;
    const int wave = tid >> 6;
    const int lane = tid & 63;
    const int lrow = lane & 15;
    const int quad = lane >> 4;

    short8 qf[2];
    #pragma unroll
    for (int m = 0; m < 2; ++m) {
        const int j  = blockIdx.y * 128 + wave * 32 + m * 16 + lrow;
        const int pq = base + rr * j;
        qf[m] = *(const short8*)(q + (size_t)pq * qs + head * HDSZ + quad * 8);
    }

    f32x4 acc[2][2];
    float lsum[2] = {0.f, 0.f};        // per-lane partial, q = lrow
    #pragma unroll
    for (int m = 0; m < 2; ++m)
        #pragma unroll
        for (int dt = 0; dt < 2; ++dt) acc[m][dt] = (f32x4){0.f, 0.f, 0.f, 0.f};

    const int skr = tid >> 2;          // 0..63 (k row staged by this thread)
    const int sdb = (tid & 3) * 8;     // 0,8,16,24 (d offset staged)
    const int grp = tid & 3;           // = sdb>>3
    const int wcol = (2 * skr + 32 * grp) & 127;   // rotated byte col for V^T write

    // load step 0
    size_t prow = (size_t)(base + rr * skr) * qs + head * HDSZ + sdb;
    uint4 kreg = *(const uint4*)(k + prow);
    uint4 vreg = *(const uint4*)(v + prow);

    // stage step 0 into buf 0
    *(uint4*)&Kb[0][skr][sdb] = kreg;
    {
        const ushort* vp = (const ushort*)&vreg;
        #pragma unroll
        for (int i = 0; i < 8; ++i)
            *(ushort*)((char*)&Vt[0][sdb + i][0] + wcol) = vp[i];
    }

    int cur = 0;
    for (int kc = 0; kc < kEnd; kc += 64) {
        __syncthreads();               // buf[cur] ready for all waves
        const bool more = (kc + 64 < kEnd);
        if (more) {                    // prefetch next step (global)
            prow = (size_t)(base + rr * (kc + 64 + skr)) * qs + head * HDSZ + sdb;
            kreg = *(const uint4*)(k + prow);
            vreg = *(const uint4*)(v + prow);
        }

        short8 kf[4];
        #pragma unroll
        for (int t = 0; t < 4; ++t)
            kf[t] = *(const short8*)&Kb[cur][t * 16 + lrow][quad * 8];

        short8 vf[2][2];
        #pragma unroll
        for (int g = 0; g < 2; ++g)
            #pragma unroll
            for (int dt = 0; dt < 2; ++dt) {
                const int row  = dt * 16 + lrow;
                const int rotb = 32 * ((row >> 3) & 3);
                const int cb0  = (64 * g + 8 * quad + rotb) & 127;
                const int cb1  = (64 * g + 8 * quad + 32 + rotb) & 127;
                vf[g][dt] = cat44(*(const short4v*)((const char*)&Vt[cur][row][0] + cb0),
                                  *(const short4v*)((const char*)&Vt[cur][row][0] + cb1));
            }

        #pragma unroll
        for (int m = 0; m < 2; ++m) {
            f32x4 sc[4];
            #pragma unroll
            for (int t = 0; t < 4; ++t)       // SWAPPED: P^T fragments
                sc[t] = __builtin_amdgcn_mfma_f32_16x16x32_bf16(
                            kf[t], qf[m], (f32x4){0.f,0.f,0.f,0.f}, 0, 0, 0);
            float p[4][4];
            #pragma unroll
            for (int t = 0; t < 4; ++t)
                #pragma unroll
                for (int rg = 0; rg < 4; ++rg)
                    p[t][rg] = exp2f(sc[t][rg]);     // Q pre-scaled in gemm
            float ps = 0.f;
            #pragma unroll
            for (int t = 0; t < 4; ++t)
                ps += (p[t][0] + p[t][1]) + (p[t][2] + p[t][3]);
            lsum[m] += ps;
            unsigned pw[4][2];
            #pragma unroll
            for (int t = 0; t < 4; ++t) {
                pw[t][0] = cvtpk_bf16(p[t][0], p[t][1]);
                pw[t][1] = cvtpk_bf16(p[t][2], p[t][3]);
            }
            #pragma unroll
            for (int g = 0; g < 2; ++g) {
                union { short8 s; unsigned u[4]; } pa;
                pa.u[0] = pw[2 * g][0];
                pa.u[1] = pw[2 * g][1];
                pa.u[2] = pw[2 * g + 1][0];
                pa.u[3] = pw[2 * g + 1][1];
                #pragma unroll
                for (int dt = 0; dt < 2; ++dt)
                    acc[m][dt] = __builtin_amdgcn_mfma_f32_16x16x32_bf16(
                                     pa.s, vf[g][dt], acc[m][dt], 0, 0, 0);
            }
        }

        if (more) {                    // stage next step into the other buffer
            *(uint4*)&Kb[cur ^ 1][skr][sdb] = kreg;
            const ushort* vp = (const ushort*)&vreg;
            #pragma unroll
            for (int i = 0; i < 8; ++i)
                *(ushort*)((char*)&Vt[cur ^ 1][sdb + i][0] + wcol) = vp[i];
        }
        cur ^= 1;
    }

    #pragma unroll
    for (int m = 0; m < 2; ++m) {
        float tot = lsum[m];
        tot += __shfl_xor(tot, 16, 64);
        tot += __shfl_xor(tot, 32, 64);    // all quads now hold sum for q=lrow
        #pragma unroll
        for (int rg = 0; rg < 4; ++rg) {
            const float li = __shfl(tot, quad * 4 + rg, 16);  // sum for q=quad*4+rg
            const int j  = blockIdx.y * 128 + wave * 32 + m * 16 + quad * 4 + rg;
            const int pq = base + rr * j;
            const float inv = 1.0f / li;
            float* dst = bo5 + ((size_t)b2 * S_TOT + pq) * DD + head * HDSZ;
            dst[lrow]      = acc[m][0][rg] * inv;
            dst[16 + lrow] = acc[m][1][rg] * inv;
            if (lrow == 0)
                lse5[((size_t)b2 * S_TOT + pq) * NHEAD + head] = __logf(li);
        }
    }
}

// ============ combine 5 branches (layer 0), bf16 out ============
__global__ __launch_bounds__(256)
void combine_kernel(const float* __restrict__ bo5, const float* __restrict__ lse5,
                    ushort* __restrict__ attn)
{
    const int p = blockIdx.x;
    const int d = threadIdx.x;
    const int h = d >> 5;
    float lse[5];
    bool sel[5];
    float mx = -3.0e38f;
    #pragma unroll
    for (int b2 = 0; b2 < 5; ++b2) {
        const int r = 1 << b2;
        sel[b2] = ((p & (r - 1)) == (h & (r - 1)));
        if (sel[b2]) {
            lse[b2] = lse5[((size_t)b2 * S_TOT + p) * NHEAD + h];
            mx = fmaxf(mx, lse[b2]);
        }
    }
    float wsum = 0.f, acc = 0.f;
    #pragma unroll
    for (int b2 = 0; b2 < 5; ++b2) {
        if (sel[b2]) {
            const float wgt = __expf(lse[b2] - mx);
            wsum += wgt;
            acc += wgt * bo5[((size_t)b2 * S_TOT + p) * DD + d];
        }
    }
    attn[(size_t)p * DD + d] = f2bf(acc / wsum);
}

// ============ FUSED layer-1 tail: qrow + row0-attn + mid + ffn1 + ffn2 + final
// One 256-thread block; all intermediates in LDS (no same-block global
// read-after-write). Replaces 6 tiny launches. Math verbatim per phase.
__global__ __launch_bounds__(256)
void tail_fused_kernel(const float* __restrict__ h,
                       const float* __restrict__ g1, const float* __restrict__ b1l,
                       const ushort* __restrict__ wbuf,
                       const float* __restrict__ bq1,
                       const ushort* __restrict__ kv,      // layer1 K at +0, V at +256, stride 512
                       const float* __restrict__ bo1,
                       const float* __restrict__ g2, const float* __restrict__ b2l,
                       const float* __restrict__ b11, const float* __restrict__ b21,
                       const float* __restrict__ eg, const float* __restrict__ eb,
                       const float* __restrict__ ng, const float* __restrict__ nb,
                       float* __restrict__ out)
{
    __shared__ float red[4];
    __shared__ float qrow_s[256];
    __shared__ float bo_r0[5][256];
    __shared__ float lse_r0[5][8];
    __shared__ float fs[256];          // scratch: as / att / f
    __shared__ float ms1[1024];
    __shared__ float hv_s[256];
    __shared__ float ms2[4][64], ls2[4][64];
    __shared__ float os2[4][64][32];

    const int tid  = threadIdx.x;
    const int wave = tid >> 6;
    const int lane = tid & 63;

    // ---- phase 1: qrow = LN1(h row0) @ Wq1 + bq1 ----
    {
        const float xv = h[tid];
        const float mu = block_sum256(xv, red) * (1.0f / 256.0f);
        const float dv = xv - mu;
        const float var = block_sum256(dv * dv, red) * (1.0f / 256.0f);
        fs[tid] = dv * rsqrtf(var + 1e-5f) * g1[tid] + b1l[tid];
        __syncthreads();
        float acc = 0.f;
        const ushort* Wt = wbuf + OFF_WQ1;
        for (int k2 = 0; k2 < 256; k2 += 8) {
            const short8 w8 = *(const short8*)&Wt[(size_t)tid * 256 + k2];
            #pragma unroll
            for (int j = 0; j < 8; ++j) acc += fs[k2 + j] * bf2f((ushort)w8[j]);
        }
        qrow_s[tid] = acc + bq1[tid];
        __syncthreads();
    }

    // ---- phase 2: row0 attention, 16 (b2,head) units, 4 per wave ----
    for (int ui = 0; ui < 4; ++ui) {
        const int u = wave * 4 + ui;
        int b2, head;
        if (u < 8)        { b2 = 0; head = u; }
        else if (u < 12)  { b2 = 1; head = (u - 8) * 2; }
        else if (u < 14)  { b2 = 2; head = (u - 12) * 4; }
        else if (u == 14) { b2 = 3; head = 0; }
        else              { b2 = 4; head = 0; }
        const int r = 1 << b2;
        float qreg[32];
        #pragma unroll
        for (int d = 0; d < 32; ++d) qreg[d] = qrow_s[head * 32 + d];
        float m = -3.0e38f, l = 0.f, o[32];
        #pragma unroll
        for (int d = 0; d < 32; ++d) o[d] = 0.f;
        for (int j = lane; j < 1024; j += 64) {
            const int pk = r * j;
            float s;
            if (pk < S_TOT) {
                float s0 = 0.f;
                #pragma unroll
                for (int d = 0; d < 32; d += 8) {
                    const uint4 raw = *(const uint4*)(kv + (size_t)pk * 512 + head * 32 + d);
                    const ushort* kp = (const ushort*)&raw;
                    #pragma unroll
                    for (int i = 0; i < 8; ++i) s0 += qreg[d + i] * bf2f(kp[i]);
                }
                s = s0 * ATT_SCALE;
            } else s = -1.0e9f;
            const float mn = fmaxf(m, s);
            const float c = __expf(m - mn);
            const float e = __expf(s - mn);
            l = l * c + e; m = mn;
            if (pk < S_TOT) {
                #pragma unroll
                for (int d = 0; d < 32; d += 8) {
                    const uint4 raw = *(const uint4*)(kv + 256 + (size_t)pk * 512 + head * 32 + d);
                    const ushort* vp = (const ushort*)&raw;
                    #pragma unroll
                    for (int i = 0; i < 8; ++i) o[d + i] = o[d + i] * c + e * bf2f(vp[i]);
                }
            } else {
                #pragma unroll
                for (int d = 0; d < 32; ++d) o[d] *= c;
            }
        }
        ms2[wave][lane] = m; ls2[wave][lane] = l;
        #pragma unroll
        for (int d = 0; d < 32; ++d) os2[wave][lane][d] = o[d];
        __syncthreads();
        for (int st = 32; st >= 1; st >>= 1) {
            if (lane < st) {
                const float m2 = ms2[wave][lane + st], l2 = ls2[wave][lane + st];
                const float mn = fmaxf(ms2[wave][lane], m2);
                const float c1 = __expf(ms2[wave][lane] - mn);
                const float c2 = __expf(m2 - mn);
                ls2[wave][lane] = ls2[wave][lane] * c1 + l2 * c2;
                ms2[wave][lane] = mn;
                for (int d = 0; d < 32; ++d)
                    os2[wave][lane][d] = os2[wave][lane][d] * c1 + os2[wave][lane + st][d] * c2;
            }
            __syncthreads();
        }
        if (lane < 32) bo_r0[b2][head * 32 + lane] = os2[wave][0][lane] / ls2[wave][0];
        if (lane == 0) lse_r0[b2][head] = ms2[wave][0] + __logf(ls2[wave][0]);
        __syncthreads();
    }

    // ---- phase 3: mid = combine(row0) @ Wo1 + residual; LN2 -> f ----
    float hv;
    {
        const int hh = tid >> 5;
        float lse[5]; bool sel[5]; float mx = -3.0e38f;
        #pragma unroll
        for (int bb = 0; bb < 5; ++bb) {
            const int r = 1 << bb;
            sel[bb] = ((hh & (r - 1)) == 0);
            if (sel[bb]) {
                lse[bb] = lse_r0[bb][hh];
                mx = fmaxf(mx, lse[bb]);
            }
        }
        float wsum = 0.f, acc = 0.f;
        #pragma unroll
        for (int bb = 0; bb < 5; ++bb) {
            if (sel[bb]) {
                const float wgt = __expf(lse[bb] - mx);
                wsum += wgt;
                acc += wgt * bo_r0[bb][tid];
            }
        }
        fs[tid] = acc / wsum;          // att
        __syncthreads();
        float a2 = 0.f;
        const ushort* Wo1t = wbuf + OFF_WO1;
        for (int k2 = 0; k2 < 256; k2 += 8) {
            const short8 w8 = *(const short8*)&Wo1t[(size_t)tid * 256 + k2];
            #pragma unroll
            for (int j = 0; j < 8; ++j) a2 += fs[k2 + j] * bf2f((ushort)w8[j]);
        }
        hv = a2 + bo1[tid] + h[tid];
        hv_s[tid] = hv;
        const float mu = block_sum256(hv, red) * (1.0f / 256.0f);
        const float dv = hv - mu;
        const float var = block_sum256(dv * dv, red) * (1.0f / 256.0f);
        __syncthreads();               // fs (att) reads done before overwrite
        fs[tid] = dv * rsqrtf(var + 1e-5f) * g2[tid] + b2l[tid];   // f
        __syncthreads();
    }

    // ---- phase 4: ffn1 (1024 outputs, gelu) ----
    {
        const ushort* W11t = wbuf + OFF_W11;
        for (int nn = 0; nn < 4; ++nn) {
            const int n = nn * 256 + tid;
            float acc = 0.f;
            for (int k2 = 0; k2 < 256; k2 += 8) {
                const short8 w8 = *(const short8*)&W11t[(size_t)n * 256 + k2];
                #pragma unroll
                for (int j = 0; j < 8; ++j) acc += fs[k2 + j] * bf2f((ushort)w8[j]);
            }
            ms1[n] = gelu_exact(acc + b11[n]);
        }
        __syncthreads();
    }

    // ---- phase 5: ffn2 (256 outputs, 4 lanes each) ----
    {
        const ushort* W21t = wbuf + OFF_W21;
        for (int bb = 0; bb < 4; ++bb) {
            const int n  = bb * 64 + (tid >> 2);
            const int kq = (tid & 3) * 256;
            float acc = 0.f;
            for (int k2 = 0; k2 < 256; k2 += 8) {
                const short8 w8 = *(const short8*)&W21t[(size_t)n * 1024 + kq + k2];
                #pragma unroll
                for (int j = 0; j < 8; ++j) acc += ms1[kq + k2 + j] * bf2f((ushort)w8[j]);
            }
            acc += __shfl_xor(acc, 1);
            acc += __shfl_xor(acc, 2);
            if ((tid & 3) == 0) hv_s[n] = hv_s[n] + acc + b21[n];
        }
        __syncthreads();
    }

    // ---- phase 6: final double-LN -> out ----
    {
        float xv = hv_s[tid];
        {
            const float mu = block_sum256(xv, red) * (1.0f / 256.0f);
            const float dv = xv - mu;
            const float var = block_sum256(dv * dv, red) * (1.0f / 256.0f);
            xv = dv * rsqrtf(var + 1e-5f) * eg[tid] + eb[tid];
        }
        {
            const float mu = block_sum256(xv, red) * (1.0f / 256.0f);
            const float dv = xv - mu;
            const float var = block_sum256(dv * dv, red) * (1.0f / 256.0f);
            out[tid] = dv * rsqrtf(var + 1e-5f) * ng[tid] + nb[tid];
        }
    }
}

extern "C" void kernel_launch(void* const* d_in, const int* in_sizes, int n_in,
                              void* d_out, int out_size, void* d_ws, size_t ws_size,
                              hipStream_t stream)
{
    const float* x      = (const float*)d_in[0];
    const int*   coords = (const int*)  d_in[1];
    const float* proj_w = (const float*)d_in[2];
    const float* proj_b = (const float*)d_in[3];
    const float* cls_tok= (const float*)d_in[4];
    const float* Wq     = (const float*)d_in[5];
    const float* Wk     = (const float*)d_in[6];
    const float* Wv     = (const float*)d_in[7];
    const float* Wo     = (const float*)d_in[8];
    const float* bq     = (const float*)d_in[9];
    const float* bk     = (const float*)d_in[10];
    const float* bv     = (const float*)d_in[11];
    const float* bo_    = (const float*)d_in[12];
    const float* ln1_g  = (const float*)d_in[13];
    const float* ln1_b  = (const float*)d_in[14];
    const float* ln2_g  = (const float*)d_in[15];
    const float* ln2_b  = (const float*)d_in[16];
    const float* W1     = (const float*)d_in[17];
    const float* b1     = (const float*)d_in[18];
    const float* W2     = (const float*)d_in[19];
    const float* b2v    = (const float*)d_in[20];
    const float* enc_g  = (const float*)d_in[21];
    const float* enc_b  = (const float*)d_in[22];
    const float* norm_g = (const float*)d_in[23];
    const float* norm_b = (const float*)d_in[24];
    float* out = (float*)d_out;

    const size_t SD = (size_t)S_TOT * DD;      // 2,097,152
    float* ws   = (float*)d_ws;
    float* h    = ws;                          // SD fp32
    float* big  = h + SD;                      // 5*SD fp32: bo5 | xbf | midbf overlay
    float* bo5  = big;
    ushort* xbf   = (ushort*)big;              // 8191*1536 ushort
    ushort* midbf = (ushort*)big;              // 8192*1024 ushort
    float* lse5 = big + 5 * SD;                // 327,680 fp32
    ushort* a_bf    = (ushort*)(lse5 + 5 * S_TOT * NHEAD);   // SD ushort
    ushort* qkv_bf  = a_bf + SD;               // 3*SD ushort
    ushort* attn_bf = qkv_bf + 3 * SD;         // SD ushort
    ushort* wbuf    = attn_bf + SD;            // WBUF_TOT ushort
    float* bqkv0  = (float*)(wbuf + WBUF_TOT); // 768
    float* bkv1   = bqkv0 + 768;               // 512

    auto gemm64 = [&](const ushort* A, const ushort* Bt, const float* bias, void* C,
                      int M, int N, int K, int flags) {
        gemm4_kernel<64><<<128 * (N / 64), 256, 0, stream>>>(A, Bt, bias, C, M, N, K,
                                                             flags, coords);
    };

    // ---- setup ----
    setup_kernel<<<6627, 256, 0, stream>>>(x, proj_w, Wq, Wk, Wv, Wo, W1, W2,
                                           bq, bk, bv, cls_tok, wbuf, bqkv0, bkv1,
                                           xbf, h);

    // ---- projection (+ fused pos-embed) ----
    gemm64(xbf, wbuf + OFF_PROJ, proj_b, h + DD, 8191, 256, 1536, 8);

    // ---- layer 0 ----
    ln_kernel<<<S_TOT / 4, 256, 0, stream>>>(h, ln1_g, ln1_b, a_bf);
    gemm64(a_bf, wbuf + OFF_WQ0, bqkv0, qkv_bf, 8192, 768, 256, 4 | 16); // QKV, Q pre-scaled
    attn_mfma_kernel<<<dim3(128, 8), 256, 0, stream>>>(qkv_bf, qkv_bf + 256,
                                                       qkv_bf + 512, bo5, lse5, 768);
    combine_kernel<<<S_TOT, 256, 0, stream>>>(bo5, lse5, attn_bf);
    gemm64(attn_bf, wbuf + OFF_WO0, bo_, h, 8192, 256, 256, 1);          // Wo, acc
    ln_kernel<<<S_TOT / 4, 256, 0, stream>>>(h, ln2_g, ln2_b, a_bf);
    gemm64(a_bf, wbuf + OFF_W10, b1, midbf, 8192, 1024, 256, 4 | 2);     // FFN1 gelu
    gemm64(midbf, wbuf + OFF_W20, b2v, h, 8192, 256, 1024, 1);           // FFN2, acc

    // ---- layer 1 (pruned): ln + KV gemm + ONE fused tail block ----
    ln_kernel<<<S_TOT / 4, 256, 0, stream>>>(h, ln1_g + 256, ln1_b + 256, a_bf);
    gemm64(a_bf, wbuf + OFF_WK1, bkv1, qkv_bf, 8192, 512, 256, 4);       // K,V
    tail_fused_kernel<<<1, 256, 0, stream>>>(h, ln1_g + 256, ln1_b + 256, wbuf,
                                             bq + 256, qkv_bf, bo_ + 256,
                                             ln2_g + 256, ln2_b + 256,
                                             b1 + 1024, b2v + 256,
                                             enc_g, enc_b, norm_g, norm_b, out);
}

// Round 10
// 373.342 us; speedup vs baseline: 1.2402x; 1.2402x over previous
//
#include <hip/hip_runtime.h>
#include <math.h>

#define S_TOT 8192
#define DD 256
#define NHEAD 8
#define HDSZ 32
#define ATT_SCALE 0.17677669529663687f
#define ATT_SCALE_LOG2E 0.25506601f   // ATT_SCALE * log2(e)

typedef short short8 __attribute__((ext_vector_type(8)));
typedef short short4v __attribute__((ext_vector_type(4)));
typedef float f32x4 __attribute__((ext_vector_type(4)));
typedef unsigned short ushort;

// wbuf offsets (ushort elements)
#define OFF_PROJ 0
#define OFF_WQ0  393216
#define OFF_WK0  458752
#define OFF_WV0  524288
#define OFF_WO0  589824
#define OFF_W10  655360
#define OFF_W20  917504
#define OFF_WK1  1179648
#define OFF_WV1  1245184
#define OFF_WQ1  1310720
#define OFF_WO1  1376256
#define OFF_W11  1441792
#define OFF_W21  1703936
#define WBUF_TOT 1966080

__device__ inline ushort f2bf(float f) {
    union { float f; unsigned u; } c; c.f = f;
    unsigned u = c.u;
    u += 0x7fffu + ((u >> 16) & 1u);          // RNE
    return (ushort)(u >> 16);
}
__device__ inline float bf2f(ushort u) {
    union { unsigned u; float f; } c; c.u = ((unsigned)u) << 16;
    return c.f;
}
__device__ inline float gelu_exact(float v) {
    return 0.5f * v * (1.0f + erff(v * 0.7071067811865475f));
}
__device__ inline unsigned cvtpk_bf16(float a, float b) {
    unsigned r;
    asm("v_cvt_pk_bf16_f32 %0, %1, %2" : "=v"(r) : "v"(a), "v"(b));
    return r;   // low16 = bf16(a), high16 = bf16(b), RNE
}
__device__ inline short8 cat44(short4v a, short4v b) {
    return __builtin_shufflevector(a, b, 0, 1, 2, 3, 4, 5, 6, 7);
}
__device__ inline float block_sum256(float v, float* red) {
    #pragma unroll
    for (int off = 32; off > 0; off >>= 1) v += __shfl_down(v, off, 64);
    const int wid = threadIdx.x >> 6, lane = threadIdx.x & 63;
    if (lane == 0) red[wid] = v;
    __syncthreads();
    const float s = red[0] + red[1] + red[2] + red[3];
    __syncthreads();
    return s;
}

// ============ setup: weight transposes + bias concat + x->bf16 + cls ============
__global__ __launch_bounds__(256)
void setup_kernel(const float* __restrict__ x, const float* __restrict__ proj_w,
                  const float* __restrict__ Wq, const float* __restrict__ Wk,
                  const float* __restrict__ Wv, const float* __restrict__ Wo,
                  const float* __restrict__ W1, const float* __restrict__ W2,
                  const float* __restrict__ bq, const float* __restrict__ bk,
                  const float* __restrict__ bv, const float* __restrict__ cls_tok,
                  ushort* __restrict__ wbuf, float* __restrict__ bqkv0,
                  float* __restrict__ bkv1, ushort* __restrict__ xbf,
                  float* __restrict__ h)
{
    const int b = blockIdx.x;
    const int t = threadIdx.x;
    if (b >= 482) {
        if (b == 6626) { h[t] = cls_tok[t]; return; }   // cls (tab[0]==0)
        const int i = (b - 482) * 256 + t;
        const int n8 = 8191 * 1536 / 8;
        if (i >= n8) return;
        const float4 a0 = *(const float4*)(x + (size_t)i * 8);
        const float4 a1 = *(const float4*)(x + (size_t)i * 8 + 4);
        ushort tmp[8] = { f2bf(a0.x), f2bf(a0.y), f2bf(a0.z), f2bf(a0.w),
                          f2bf(a1.x), f2bf(a1.y), f2bf(a1.z), f2bf(a1.w) };
        *(uint4*)(xbf + (size_t)i * 8) = *(const uint4*)tmp;
        return;
    }
    if (b >= 480) {
        if (b == 480) {
            for (int i = t; i < 768; i += 256)
                bqkv0[i] = (i < 256) ? bq[i] : ((i < 512) ? bk[i - 256] : bv[i - 512]);
        } else {
            for (int i = t; i < 512; i += 256)
                bkv1[i] = (i < 256) ? bk[256 + i] : bv[i];
        }
        return;
    }
    const float* src; ushort* dst; int R, C, t0;
    if (b < 96)       { src = proj_w;        dst = wbuf + OFF_PROJ; R = 1536; C = 256;  t0 = 0;   }
    else if (b < 112) { src = Wq;            dst = wbuf + OFF_WQ0;  R = 256;  C = 256;  t0 = 96;  }
    else if (b < 128) { src = Wk;            dst = wbuf + OFF_WK0;  R = 256;  C = 256;  t0 = 112; }
    else if (b < 144) { src = Wv;            dst = wbuf + OFF_WV0;  R = 256;  C = 256;  t0 = 128; }
    else if (b < 160) { src = Wo;            dst = wbuf + OFF_WO0;  R = 256;  C = 256;  t0 = 144; }
    else if (b < 224) { src = W1;            dst = wbuf + OFF_W10;  R = 256;  C = 1024; t0 = 160; }
    else if (b < 288) { src = W2;            dst = wbuf + OFF_W20;  R = 1024; C = 256;  t0 = 224; }
    else if (b < 304) { src = Wk + 65536;    dst = wbuf + OFF_WK1;  R = 256;  C = 256;  t0 = 288; }
    else if (b < 320) { src = Wv + 65536;    dst = wbuf + OFF_WV1;  R = 256;  C = 256;  t0 = 304; }
    else if (b < 336) { src = Wq + 65536;    dst = wbuf + OFF_WQ1;  R = 256;  C = 256;  t0 = 320; }
    else if (b < 352) { src = Wo + 65536;    dst = wbuf + OFF_WO1;  R = 256;  C = 256;  t0 = 336; }
    else if (b < 416) { src = W1 + 262144;   dst = wbuf + OFF_W11;  R = 256;  C = 1024; t0 = 352; }
    else              { src = W2 + 262144;   dst = wbuf + OFF_W21;  R = 1024; C = 256;  t0 = 416; }
    const int lt = b - t0;
    const int tC = C >> 6;
    const int tr = lt / tC, tc = lt % tC;
    __shared__ ushort tile[64][68];
    const int col = t & 63;
    const int r4  = t >> 6;
    #pragma unroll
    for (int i = 0; i < 16; ++i) {
        const int row = i * 4 + r4;
        tile[row][col] = f2bf(src[(size_t)(tr * 64 + row) * C + tc * 64 + col]);
    }
    __syncthreads();
    #pragma unroll
    for (int i = 0; i < 16; ++i) {
        const int n = i * 4 + r4;
        dst[(size_t)(tc * 64 + n) * R + tr * 64 + col] = tile[col][n];
    }
}

// ============ LayerNorm over D=256: one ROW PER WAVE, no barriers ============
__global__ __launch_bounds__(256)
void ln_kernel(const float* __restrict__ in, const float* __restrict__ g,
               const float* __restrict__ b, ushort* __restrict__ outp)
{
    const int row  = blockIdx.x * 4 + (threadIdx.x >> 6);
    const int lane = threadIdx.x & 63;
    const float4 xv = *(const float4*)(in + (size_t)row * DD + lane * 4);
    float s = (xv.x + xv.y) + (xv.z + xv.w);
    #pragma unroll
    for (int off = 32; off > 0; off >>= 1) s += __shfl_xor(s, off, 64);
    const float mu = s * (1.0f / 256.0f);
    const float dx = xv.x - mu, dy = xv.y - mu, dz = xv.z - mu, dw = xv.w - mu;
    float v2 = (dx * dx + dy * dy) + (dz * dz + dw * dw);
    #pragma unroll
    for (int off = 32; off > 0; off >>= 1) v2 += __shfl_xor(v2, off, 64);
    const float rs = rsqrtf(v2 * (1.0f / 256.0f) + 1e-5f);
    const float4 gv = *(const float4*)(g + lane * 4);
    const float4 bv = *(const float4*)(b + lane * 4);
    uint2 w;
    w.x = cvtpk_bf16(dx * rs * gv.x + bv.x, dy * rs * gv.y + bv.y);
    w.y = cvtpk_bf16(dz * rs * gv.z + bv.z, dw * rs * gv.w + bv.w);
    *(uint2*)(outp + (size_t)row * DD + lane * 4) = w;
}

// ============ gemm4: BM=64 x BN=64, BK=64, XCD-swizzled 1-D grid ============
// C = [C +] act(A @ Bt^T + bias) [+ pos].  A bf16 MxK, Bt bf16 NxK.
// flags: 1 = acc into fp32 C, 2 = GELU, 4 = bf16 out, 8 = pos-embed,
//        16 = scale cols<256 by ATT_SCALE_LOG2E (pre-scaled Q for attn).
// T3+T4 pipeline: 3 LDS buffers, depth-2 global_load_lds prefetch, counted
// s_waitcnt vmcnt(4) + raw s_barrier, ONE barrier per k-step.
template <int BN>
__global__ __launch_bounds__(256)
void gemm4_kernel(const ushort* __restrict__ A, const ushort* __restrict__ Bt,
                  const float* __restrict__ bias, void* __restrict__ Cv,
                  int M, int N, int K, int flags, const int* __restrict__ coords)
{
    __shared__ ushort As[3][64][64];
    __shared__ ushort Bs[3][BN][64];
    constexpr int NT = BN / 32;                // MFMA n-tiles per wave
    const int nx  = N / BN;
    const int ny8 = gridDim.x / (8 * nx);      // m-slabs per XCD (=16)
    const int b   = blockIdx.x;
    const int c8  = b & 7;
    const int j   = b >> 3;
    const int m0  = (c8 * ny8 + j / nx) * 64;
    const int n0  = (j % nx) * BN;

    const int tid  = threadIdx.x;
    const int wave = tid >> 6;
    const int lane = tid & 63;
    const int lrow = lane & 15;
    const int quad = lane >> 4;
    const int wr = (wave >> 1) * 32;           // {0,32}
    const int wc = (wave & 1) * (BN / 2);      // {0,BN/2}

    float* Cf  = (float*)Cv;
    ushort* Cb = (ushort*)Cv;

    f32x4 acc[2][NT];
    #pragma unroll
    for (int mt = 0; mt < 2; ++mt)
        #pragma unroll
        for (int nt = 0; nt < NT; ++nt)
            acc[mt][nt] = (f32x4){0.f, 0.f, 0.f, 0.f};

    const int srow = tid >> 3;                 // 0..31 row within chunk
    const int scol = (tid & 7) * 16;           // byte col 0..112

    #define STAGE(BUF, KK)                                                        \
    do {                                                                          \
        _Pragma("unroll")                                                         \
        for (int c = 0; c < 2; ++c) {                                             \
            const int row = c * 32 + srow;                                        \
            const int sb  = scol ^ ((row & 7) << 4);                              \
            const ushort* srcp = A + (size_t)(m0 + row) * K + (KK) + (sb >> 1);   \
            __builtin_amdgcn_global_load_lds(                                     \
                (const __attribute__((address_space(1))) void*)srcp,              \
                (__attribute__((address_space(3))) void*)&As[BUF][c * 32 + wave * 8][0], \
                16, 0, 0);                                                        \
        }                                                                         \
        _Pragma("unroll")                                                         \
        for (int c = 0; c < BN / 32; ++c) {                                       \
            const int row = c * 32 + srow;                                        \
            const int sb  = scol ^ ((row & 7) << 4);                              \
            const ushort* srcp = Bt + (size_t)(n0 + row) * K + (KK) + (sb >> 1);  \
            __builtin_amdgcn_global_load_lds(                                     \
                (const __attribute__((address_space(1))) void*)srcp,              \
                (__attribute__((address_space(3))) void*)&Bs[BUF][c * 32 + wave * 8][0], \
                16, 0, 0);                                                        \
        }                                                                         \
    } while (0)

    #define COMPUTE(BUF)                                                          \
    do {                                                                          \
        _Pragma("unroll")                                                         \
        for (int ks = 0; ks < 2; ++ks) {                                          \
            short8 af[2], bfr[NT];                                                \
            _Pragma("unroll")                                                     \
            for (int mt = 0; mt < 2; ++mt) {                                      \
                const int row = wr + mt * 16 + lrow;                              \
                const int cb  = (ks * 64 + quad * 16) ^ ((row & 7) << 4);         \
                af[mt] = *(const short8*)((const char*)&As[BUF][row][0] + cb);    \
            }                                                                     \
            _Pragma("unroll")                                                     \
            for (int nt = 0; nt < NT; ++nt) {                                     \
                const int row = wc + nt * 16 + lrow;                              \
                const int cb  = (ks * 64 + quad * 16) ^ ((row & 7) << 4);         \
                bfr[nt] = *(const short8*)((const char*)&Bs[BUF][row][0] + cb);   \
            }                                                                     \
            _Pragma("unroll")                                                     \
            for (int mt = 0; mt < 2; ++mt)                                        \
                _Pragma("unroll")                                                 \
                for (int nt = 0; nt < NT; ++nt)                                   \
                    acc[mt][nt] = __builtin_amdgcn_mfma_f32_16x16x32_bf16(        \
                                      af[mt], bfr[nt], acc[mt][nt], 0, 0, 0);     \
        }                                                                         \
    } while (0)

    #define WAIT_BAR_N()                                                          \
    do {                                                                          \
        if constexpr (BN == 64) { asm volatile("s_waitcnt vmcnt(4)" ::: "memory"); } \
        else                    { asm volatile("s_waitcnt vmcnt(6)" ::: "memory"); } \
        __builtin_amdgcn_sched_barrier(0);                                        \
        __builtin_amdgcn_s_barrier();                                             \
        __builtin_amdgcn_sched_barrier(0);                                        \
    } while (0)

    #define WAIT_BAR_0()                                                          \
    do {                                                                          \
        asm volatile("s_waitcnt vmcnt(0)" ::: "memory");                          \
        __builtin_amdgcn_sched_barrier(0);                                        \
        __builtin_amdgcn_s_barrier();                                             \
        __builtin_amdgcn_sched_barrier(0);                                        \
    } while (0)

    const int ktiles = K >> 6;                 // >= 4 for all call sites
    STAGE(0, 0);
    STAGE(1, 64);
    int bt = 0;
    for (int t = 0; t < ktiles - 2; ++t) {
        WAIT_BAR_N();                          // tile t landed; t+1 in flight
        const int nb = (bt + 2 >= 3) ? bt - 1 : bt + 2;
        STAGE(nb, (t + 2) * 64);               // in flight: t+1, t+2
        COMPUTE(bt);
        bt = (bt + 1 == 3) ? 0 : bt + 1;
    }
    WAIT_BAR_N();                              // tile ktiles-2 landed
    COMPUTE(bt);
    bt = (bt + 1 == 3) ? 0 : bt + 1;
    WAIT_BAR_0();                              // tile ktiles-1 landed
    COMPUTE(bt);
    #undef STAGE
    #undef COMPUTE
    #undef WAIT_BAR_N
    #undef WAIT_BAR_0

    #pragma unroll
    for (int mt = 0; mt < 2; ++mt) {
        #pragma unroll
        for (int rg = 0; rg < 4; ++rg) {
            const int r = m0 + wr + mt * 16 + quad * 4 + rg;
            if (r >= M) continue;
            #pragma unroll
            for (int nt = 0; nt < NT; ++nt) {
                const int c = n0 + wc + nt * 16 + lrow;
                float vv = acc[mt][nt][rg] + bias[c];
                if (flags & 8) {   // pos-embed for token r (output = h row r+1)
                    const int cg = coords[2 * r + ((c < 128) ? 1 : 0)] >> 8;
                    // omega = 10000^(-(c&63)/64) = exp2(-(c&63)*log2(1e4)/64)
                    const float omega = exp2f((float)(c & 63) * -0.2076205059304703f);
                    const float o = (float)cg * omega;
                    vv += ((c & 64) == 0) ? __sinf(o) : __cosf(o);
                }
                if (flags & 16) { if (c < 256) vv *= ATT_SCALE_LOG2E; }
                if (flags & 2) vv = gelu_exact(vv);
                if (flags & 4) {
                    Cb[(size_t)r * N + c] = f2bf(vv);
                } else {
                    if (flags & 1) vv += Cf[(size_t)r * N + c];
                    Cf[(size_t)r * N + c] = vv;
                }
            }
        }
    }
}

// ============ MFMA dilated attention (bf16, no-max softmax) ============
// R7-verified version (58.5us): 4 waves/block, swapped QK^T (sc=mfma(K,Q))
// puts P lane-local; PV A-fragment = cvt_pk words in registers (zero P LDS
// traffic); B-fragment = ds_read_b64 pair from rotated Vt. Kb/Vt double-
// buffered, one barrier per k-step, 1-step register K/V prefetch.
__global__ __launch_bounds__(256)
void attn_mfma_kernel(const ushort* __restrict__ q, const ushort* __restrict__ k,
                      const ushort* __restrict__ v, float* __restrict__ bo5,
                      float* __restrict__ lse5, int qs)
{
    __shared__ ushort Kb[2][64][40];
    __shared__ ushort Vt[2][32][72];

    const int unit = blockIdx.x;
    const int segu = unit >> 3;
    const int head = unit & 7;
    int b2, n;
    if (segu < 8)        { b2 = 0; n = segu; }
    else if (segu < 12)  { b2 = 1; n = segu - 8; }
    else if (segu < 14)  { b2 = 2; n = segu - 12; }
    else if (segu == 14) { b2 = 3; n = 0; }
    else                 { b2 = 4; n = 0; }
    const int w  = 1024 << b2;
    const int rr = 1 << b2;
    const int base = n * w + (head & (rr - 1));

    int kEnd = (S_TOT - base + rr - 1) >> b2;
    if (kEnd > 1024) kEnd = 1024;
    if (blockIdx.y * 128 >= kEnd) return;

    const int tid  = threadIdx.x;
    const int wave = tid >> 6;
    const int lane = tid & 63;
    const int lrow = lane & 15;
    const int quad = lane >> 4;

    short8 qf[2];
    #pragma unroll
    for (int m = 0; m < 2; ++m) {
        const int j  = blockIdx.y * 128 + wave * 32 + m * 16 + lrow;
        const int pq = base + rr * j;
        qf[m] = *(const short8*)(q + (size_t)pq * qs + head * HDSZ + quad * 8);
    }

    f32x4 acc[2][2];
    float lsum[2] = {0.f, 0.f};        // per-lane partial, q = lrow
    #pragma unroll
    for (int m = 0; m < 2; ++m)
        #pragma unroll
        for (int dt = 0; dt < 2; ++dt) acc[m][dt] = (f32x4){0.f, 0.f, 0.f, 0.f};

    const int skr = tid >> 2;          // 0..63 (k row staged by this thread)
    const int sdb = (tid & 3) * 8;     // 0,8,16,24 (d offset staged)
    const int grp = tid & 3;           // = sdb>>3
    const int wcol = (2 * skr + 32 * grp) & 127;   // rotated byte col for V^T write

    // load step 0
    size_t prow = (size_t)(base + rr * skr) * qs + head * HDSZ + sdb;
    uint4 kreg = *(const uint4*)(k + prow);
    uint4 vreg = *(const uint4*)(v + prow);

    // stage step 0 into buf 0
    *(uint4*)&Kb[0][skr][sdb] = kreg;
    {
        const ushort* vp = (const ushort*)&vreg;
        #pragma unroll
        for (int i = 0; i < 8; ++i)
            *(ushort*)((char*)&Vt[0][sdb + i][0] + wcol) = vp[i];
    }

    int cur = 0;
    for (int kc = 0; kc < kEnd; kc += 64) {
        __syncthreads();               // buf[cur] ready for all waves
        const bool more = (kc + 64 < kEnd);
        if (more) {                    // prefetch next step (global)
            prow = (size_t)(base + rr * (kc + 64 + skr)) * qs + head * HDSZ + sdb;
            kreg = *(const uint4*)(k + prow);
            vreg = *(const uint4*)(v + prow);
        }

        short8 kf[4];
        #pragma unroll
        for (int t = 0; t < 4; ++t)
            kf[t] = *(const short8*)&Kb[cur][t * 16 + lrow][quad * 8];

        short8 vf[2][2];
        #pragma unroll
        for (int g = 0; g < 2; ++g)
            #pragma unroll
            for (int dt = 0; dt < 2; ++dt) {
                const int row  = dt * 16 + lrow;
                const int rotb = 32 * ((row >> 3) & 3);
                const int cb0  = (64 * g + 8 * quad + rotb) & 127;
                const int cb1  = (64 * g + 8 * quad + 32 + rotb) & 127;
                vf[g][dt] = cat44(*(const short4v*)((const char*)&Vt[cur][row][0] + cb0),
                                  *(const short4v*)((const char*)&Vt[cur][row][0] + cb1));
            }

        #pragma unroll
        for (int m = 0; m < 2; ++m) {
            f32x4 sc[4];
            #pragma unroll
            for (int t = 0; t < 4; ++t)       // SWAPPED: P^T fragments
                sc[t] = __builtin_amdgcn_mfma_f32_16x16x32_bf16(
                            kf[t], qf[m], (f32x4){0.f,0.f,0.f,0.f}, 0, 0, 0);
            float p[4][4];
            #pragma unroll
            for (int t = 0; t < 4; ++t)
                #pragma unroll
                for (int rg = 0; rg < 4; ++rg)
                    p[t][rg] = exp2f(sc[t][rg]);     // Q pre-scaled in gemm
            float ps = 0.f;
            #pragma unroll
            for (int t = 0; t < 4; ++t)
                ps += (p[t][0] + p[t][1]) + (p[t][2] + p[t][3]);
            lsum[m] += ps;
            unsigned pw[4][2];
            #pragma unroll
            for (int t = 0; t < 4; ++t) {
                pw[t][0] = cvtpk_bf16(p[t][0], p[t][1]);
                pw[t][1] = cvtpk_bf16(p[t][2], p[t][3]);
            }
            #pragma unroll
            for (int g = 0; g < 2; ++g) {
                union { short8 s; unsigned u[4]; } pa;
                pa.u[0] = pw[2 * g][0];
                pa.u[1] = pw[2 * g][1];
                pa.u[2] = pw[2 * g + 1][0];
                pa.u[3] = pw[2 * g + 1][1];
                #pragma unroll
                for (int dt = 0; dt < 2; ++dt)
                    acc[m][dt] = __builtin_amdgcn_mfma_f32_16x16x32_bf16(
                                     pa.s, vf[g][dt], acc[m][dt], 0, 0, 0);
            }
        }

        if (more) {                    // stage next step into the other buffer
            *(uint4*)&Kb[cur ^ 1][skr][sdb] = kreg;
            const ushort* vp = (const ushort*)&vreg;
            #pragma unroll
            for (int i = 0; i < 8; ++i)
                *(ushort*)((char*)&Vt[cur ^ 1][sdb + i][0] + wcol) = vp[i];
        }
        cur ^= 1;
    }

    #pragma unroll
    for (int m = 0; m < 2; ++m) {
        float tot = lsum[m];
        tot += __shfl_xor(tot, 16, 64);
        tot += __shfl_xor(tot, 32, 64);    // all quads now hold sum for q=lrow
        #pragma unroll
        for (int rg = 0; rg < 4; ++rg) {
            const float li = __shfl(tot, quad * 4 + rg, 16);  // sum for q=quad*4+rg
            const int j  = blockIdx.y * 128 + wave * 32 + m * 16 + quad * 4 + rg;
            const int pq = base + rr * j;
            const float inv = 1.0f / li;
            float* dst = bo5 + ((size_t)b2 * S_TOT + pq) * DD + head * HDSZ;
            dst[lrow]      = acc[m][0][rg] * inv;
            dst[16 + lrow] = acc[m][1][rg] * inv;
            if (lrow == 0)
                lse5[((size_t)b2 * S_TOT + pq) * NHEAD + head] = __logf(li);
        }
    }
}

// ============ layer-1 pruned attention: query position 0 only ============
__global__ __launch_bounds__(64)
void attn_row0_kernel(const float* __restrict__ q, const ushort* __restrict__ k,
                      const ushort* __restrict__ v, float* __restrict__ bo5,
                      float* __restrict__ lse5, int kvs)
{
    const int b2 = blockIdx.x >> 3;
    const int head = blockIdx.x & 7;
    const int r = 1 << b2;
    if (head & (r - 1)) return;
    const int tid = threadIdx.x;
    float qreg[32];
    #pragma unroll
    for (int d = 0; d < 32; d += 4) {
        const float4 t4 = *(const float4*)(q + head * HDSZ + d);
        qreg[d] = t4.x; qreg[d+1] = t4.y; qreg[d+2] = t4.z; qreg[d+3] = t4.w;
    }
    float m = -3.0e38f, l = 0.f, o[32];
    #pragma unroll
    for (int d = 0; d < 32; ++d) o[d] = 0.f;
    for (int j = tid; j < 1024; j += 64) {
        const int pk = r * j;
        float s;
        if (pk < S_TOT) {
            float s0 = 0.f;
            #pragma unroll
            for (int d = 0; d < 32; d += 8) {
                const uint4 raw = *(const uint4*)(k + (size_t)pk * kvs + head * HDSZ + d);
                const ushort* kp = (const ushort*)&raw;
                #pragma unroll
                for (int i = 0; i < 8; ++i) s0 += qreg[d + i] * bf2f(kp[i]);
            }
            s = s0 * ATT_SCALE;
        } else s = -1.0e9f;
        const float mn = fmaxf(m, s);
        const float c = __expf(m - mn);
        const float e = __expf(s - mn);
        l = l * c + e; m = mn;
        if (pk < S_TOT) {
            #pragma unroll
            for (int d = 0; d < 32; d += 8) {
                const uint4 raw = *(const uint4*)(v + (size_t)pk * kvs + head * HDSZ + d);
                const ushort* vp = (const ushort*)&raw;
                #pragma unroll
                for (int i = 0; i < 8; ++i) o[d + i] = o[d + i] * c + e * bf2f(vp[i]);
            }
        } else {
            #pragma unroll
            for (int d = 0; d < 32; ++d) o[d] *= c;
        }
    }
    __shared__ float ms[64], ls[64], os[64][32];
    ms[tid] = m; ls[tid] = l;
    #pragma unroll
    for (int d = 0; d < 32; ++d) os[tid][d] = o[d];
    __syncthreads();
    for (int st = 32; st >= 1; st >>= 1) {
        if (tid < st) {
            const float m2 = ms[tid + st], l2 = ls[tid + st];
            const float mn = fmaxf(ms[tid], m2);
            const float c1 = __expf(ms[tid] - mn);
            const float c2 = __expf(m2 - mn);
            ls[tid] = ls[tid] * c1 + l2 * c2;
            ms[tid] = mn;
            for (int d = 0; d < 32; ++d) os[tid][d] = os[tid][d]*c1 + os[tid+st][d]*c2;
        }
        __syncthreads();
    }
    if (tid < 32) bo5[(size_t)b2 * S_TOT * DD + head * HDSZ + tid] = os[0][tid] / ls[0];
    if (tid == 0) lse5[(size_t)b2 * S_TOT * NHEAD + head] = ms[0] + __logf(ls[0]);
}

// ============ combine 5 branches (layer 0), bf16 out ============
__global__ __launch_bounds__(256)
void combine_kernel(const float* __restrict__ bo5, const float* __restrict__ lse5,
                    ushort* __restrict__ attn)
{
    const int p = blockIdx.x;
    const int d = threadIdx.x;
    const int h = d >> 5;
    float lse[5];
    bool sel[5];
    float mx = -3.0e38f;
    #pragma unroll
    for (int b2 = 0; b2 < 5; ++b2) {
        const int r = 1 << b2;
        sel[b2] = ((p & (r - 1)) == (h & (r - 1)));
        if (sel[b2]) {
            lse[b2] = lse5[((size_t)b2 * S_TOT + p) * NHEAD + h];
            mx = fmaxf(mx, lse[b2]);
        }
    }
    float wsum = 0.f, acc = 0.f;
    #pragma unroll
    for (int b2 = 0; b2 < 5; ++b2) {
        if (sel[b2]) {
            const float wgt = __expf(lse[b2] - mx);
            wsum += wgt;
            acc += wgt * bo5[((size_t)b2 * S_TOT + p) * DD + d];
        }
    }
    attn[(size_t)p * DD + d] = f2bf(acc / wsum);
}

// ============ tail kernels (row 0 only) ============
__global__ __launch_bounds__(256)
void tail_qrow_kernel(const float* __restrict__ h, const float* __restrict__ g,
                      const float* __restrict__ b, const ushort* __restrict__ Wt,
                      const float* __restrict__ bias, float* __restrict__ qrow0)
{
    __shared__ float red[4];
    __shared__ float as[256];
    const int d = threadIdx.x;
    const float xv = h[d];
    const float mu = block_sum256(xv, red) * (1.0f / 256.0f);
    const float dv = xv - mu;
    const float var = block_sum256(dv * dv, red) * (1.0f / 256.0f);
    as[d] = dv * rsqrtf(var + 1e-5f) * g[d] + b[d];
    __syncthreads();
    float acc = 0.f;
    for (int k2 = 0; k2 < 256; k2 += 8) {
        const short8 w8 = *(const short8*)&Wt[(size_t)d * 256 + k2];
        #pragma unroll
        for (int j = 0; j < 8; ++j) acc += as[k2 + j] * bf2f((ushort)w8[j]);
    }
    qrow0[d] = acc + bias[d];
}

__global__ __launch_bounds__(256)
void tail_mid_kernel(const float* __restrict__ bo5, const float* __restrict__ lse5,
                     float* __restrict__ h, const ushort* __restrict__ Wo1t,
                     const float* __restrict__ bo1, const float* __restrict__ g2,
                     const float* __restrict__ b2, float* __restrict__ f)
{
    __shared__ float red[4];
    __shared__ float att[256];
    const int d = threadIdx.x;
    const int hh = d >> 5;
    float lse[5]; bool sel[5]; float mx = -3.0e38f;
    #pragma unroll
    for (int bb = 0; bb < 5; ++bb) {
        const int r = 1 << bb;
        sel[bb] = ((hh & (r - 1)) == 0);
        if (sel[bb]) {
            lse[bb] = lse5[(size_t)bb * S_TOT * NHEAD + hh];
            mx = fmaxf(mx, lse[bb]);
        }
    }
    float wsum = 0.f, acc = 0.f;
    #pragma unroll
    for (int bb = 0; bb < 5; ++bb) {
        if (sel[bb]) {
            const float wgt = __expf(lse[bb] - mx);
            wsum += wgt;
            acc += wgt * bo5[(size_t)bb * S_TOT * DD + d];
        }
    }
    att[d] = acc / wsum;
    __syncthreads();
    float a2 = 0.f;
    for (int k2 = 0; k2 < 256; k2 += 8) {
        const short8 w8 = *(const short8*)&Wo1t[(size_t)d * 256 + k2];
        #pragma unroll
        for (int j = 0; j < 8; ++j) a2 += att[k2 + j] * bf2f((ushort)w8[j]);
    }
    const float hv = a2 + bo1[d] + h[d];
    h[d] = hv;
    const float mu = block_sum256(hv, red) * (1.0f / 256.0f);
    const float dv = hv - mu;
    const float var = block_sum256(dv * dv, red) * (1.0f / 256.0f);
    f[d] = dv * rsqrtf(var + 1e-5f) * g2[d] + b2[d];
}

__global__ __launch_bounds__(256)
void tail_ffn1_kernel(const float* __restrict__ f, const ushort* __restrict__ W11t,
                      const float* __restrict__ b11, float* __restrict__ midr0)
{
    __shared__ float fs[256];
    const int tid = threadIdx.x;
    fs[tid] = f[tid];
    __syncthreads();
    const int n = blockIdx.x * 256 + tid;
    float acc = 0.f;
    for (int k2 = 0; k2 < 256; k2 += 8) {
        const short8 w8 = *(const short8*)&W11t[(size_t)n * 256 + k2];
        #pragma unroll
        for (int j = 0; j < 8; ++j) acc += fs[k2 + j] * bf2f((ushort)w8[j]);
    }
    midr0[n] = gelu_exact(acc + b11[n]);
}

__global__ __launch_bounds__(256)
void tail_ffn2_kernel(const float* __restrict__ midr0, const ushort* __restrict__ W21t,
                      const float* __restrict__ b21, float* __restrict__ h)
{
    __shared__ float ms[1024];
    const int tid = threadIdx.x;
    for (int i = tid; i < 1024; i += 256) ms[i] = midr0[i];
    __syncthreads();
    const int n  = blockIdx.x * 64 + (tid >> 2);
    const int kq = (tid & 3) * 256;
    float acc = 0.f;
    for (int k2 = 0; k2 < 256; k2 += 8) {
        const short8 w8 = *(const short8*)&W21t[(size_t)n * 1024 + kq + k2];
        #pragma unroll
        for (int j = 0; j < 8; ++j) acc += ms[kq + k2 + j] * bf2f((ushort)w8[j]);
    }
    acc += __shfl_xor(acc, 1);
    acc += __shfl_xor(acc, 2);
    if ((tid & 3) == 0) h[n] = h[n] + acc + b21[n];
}

__global__ __launch_bounds__(256)
void tail_final_kernel(const float* __restrict__ h, const float* __restrict__ eg,
                       const float* __restrict__ eb, const float* __restrict__ ng,
                       const float* __restrict__ nb, float* __restrict__ out)
{
    __shared__ float red[4];
    const int d = threadIdx.x;
    float xv = h[d];
    {
        const float mu = block_sum256(xv, red) * (1.0f / 256.0f);
        const float dv = xv - mu;
        const float var = block_sum256(dv * dv, red) * (1.0f / 256.0f);
        xv = dv * rsqrtf(var + 1e-5f) * eg[d] + eb[d];
    }
    {
        const float mu = block_sum256(xv, red) * (1.0f / 256.0f);
        const float dv = xv - mu;
        const float var = block_sum256(dv * dv, red) * (1.0f / 256.0f);
        out[d] = dv * rsqrtf(var + 1e-5f) * ng[d] + nb[d];
    }
}

extern "C" void kernel_launch(void* const* d_in, const int* in_sizes, int n_in,
                              void* d_out, int out_size, void* d_ws, size_t ws_size,
                              hipStream_t stream)
{
    const float* x      = (const float*)d_in[0];
    const int*   coords = (const int*)  d_in[1];
    const float* proj_w = (const float*)d_in[2];
    const float* proj_b = (const float*)d_in[3];
    const float* cls_tok= (const float*)d_in[4];
    const float* Wq     = (const float*)d_in[5];
    const float* Wk     = (const float*)d_in[6];
    const float* Wv     = (const float*)d_in[7];
    const float* Wo     = (const float*)d_in[8];
    const float* bq     = (const float*)d_in[9];
    const float* bk     = (const float*)d_in[10];
    const float* bv     = (const float*)d_in[11];
    const float* bo_    = (const float*)d_in[12];
    const float* ln1_g  = (const float*)d_in[13];
    const float* ln1_b  = (const float*)d_in[14];
    const float* ln2_g  = (const float*)d_in[15];
    const float* ln2_b  = (const float*)d_in[16];
    const float* W1     = (const float*)d_in[17];
    const float* b1     = (const float*)d_in[18];
    const float* W2     = (const float*)d_in[19];
    const float* b2v    = (const float*)d_in[20];
    const float* enc_g  = (const float*)d_in[21];
    const float* enc_b  = (const float*)d_in[22];
    const float* norm_g = (const float*)d_in[23];
    const float* norm_b = (const float*)d_in[24];
    float* out = (float*)d_out;

    const size_t SD = (size_t)S_TOT * DD;      // 2,097,152
    float* ws   = (float*)d_ws;
    float* h    = ws;                          // SD fp32
    float* big  = h + SD;                      // 5*SD fp32: bo5 | xbf | midbf overlay
    float* bo5  = big;
    ushort* xbf   = (ushort*)big;              // 8191*1536 ushort
    ushort* midbf = (ushort*)big;              // 8192*1024 ushort
    float* lse5 = big + 5 * SD;                // 327,680 fp32
    ushort* a_bf    = (ushort*)(lse5 + 5 * S_TOT * NHEAD);   // SD ushort
    ushort* qkv_bf  = a_bf + SD;               // 3*SD ushort
    ushort* attn_bf = qkv_bf + 3 * SD;         // SD ushort
    ushort* wbuf    = attn_bf + SD;            // WBUF_TOT ushort
    float* bqkv0  = (float*)(wbuf + WBUF_TOT); // 768
    float* bkv1   = bqkv0 + 768;               // 512
    float* qrow0  = bkv1 + 512;                // 256
    float* f_r0   = qrow0 + 256;               // 256
    float* midr0  = f_r0 + 256;                // 1024

    auto gemm64 = [&](const ushort* A, const ushort* Bt, const float* bias, void* C,
                      int M, int N, int K, int flags) {
        gemm4_kernel<64><<<128 * (N / 64), 256, 0, stream>>>(A, Bt, bias, C, M, N, K,
                                                             flags, coords);
    };

    // ---- setup ----
    setup_kernel<<<6627, 256, 0, stream>>>(x, proj_w, Wq, Wk, Wv, Wo, W1, W2,
                                           bq, bk, bv, cls_tok, wbuf, bqkv0, bkv1,
                                           xbf, h);

    // ---- projection (+ fused pos-embed) ----
    gemm64(xbf, wbuf + OFF_PROJ, proj_b, h + DD, 8191, 256, 1536, 8);

    // ---- layer 0 ----
    ln_kernel<<<S_TOT / 4, 256, 0, stream>>>(h, ln1_g, ln1_b, a_bf);
    gemm64(a_bf, wbuf + OFF_WQ0, bqkv0, qkv_bf, 8192, 768, 256, 4 | 16); // QKV, Q pre-scaled
    attn_mfma_kernel<<<dim3(128, 8), 256, 0, stream>>>(qkv_bf, qkv_bf + 256,
                                                       qkv_bf + 512, bo5, lse5, 768);
    combine_kernel<<<S_TOT, 256, 0, stream>>>(bo5, lse5, attn_bf);
    gemm64(attn_bf, wbuf + OFF_WO0, bo_, h, 8192, 256, 256, 1);          // Wo, acc
    ln_kernel<<<S_TOT / 4, 256, 0, stream>>>(h, ln2_g, ln2_b, a_bf);
    gemm64(a_bf, wbuf + OFF_W10, b1, midbf, 8192, 1024, 256, 4 | 2);     // FFN1 gelu
    gemm64(midbf, wbuf + OFF_W20, b2v, h, 8192, 256, 1024, 1);           // FFN2, acc

    // ---- layer 1 (pruned) ----
    ln_kernel<<<S_TOT / 4, 256, 0, stream>>>(h, ln1_g + 256, ln1_b + 256, a_bf);
    gemm64(a_bf, wbuf + OFF_WK1, bkv1, qkv_bf, 8192, 512, 256, 4);       // K,V
    tail_qrow_kernel<<<1, 256, 0, stream>>>(h, ln1_g + 256, ln1_b + 256,
                                            wbuf + OFF_WQ1, bq + 256, qrow0);
    attn_row0_kernel<<<40, 64, 0, stream>>>(qrow0, qkv_bf, qkv_bf + 256, bo5, lse5, 512);
    tail_mid_kernel<<<1, 256, 0, stream>>>(bo5, lse5, h, wbuf + OFF_WO1, bo_ + 256,
                                           ln2_g + 256, ln2_b + 256, f_r0);
    tail_ffn1_kernel<<<4, 256, 0, stream>>>(f_r0, wbuf + OFF_W11, b1 + 1024, midr0);
    tail_ffn2_kernel<<<4, 256, 0, stream>>>(midr0, wbuf + OFF_W21, b2v + 256, h);
    tail_final_kernel<<<1, 256, 0, stream>>>(h, enc_g, enc_b, norm_g, norm_b, out);
}

// Round 11
// 358.451 us; speedup vs baseline: 1.2917x; 1.0415x over previous
//
#include <hip/hip_runtime.h>
#include <math.h>

#define S_TOT 8192
#define DD 256
#define NHEAD 8
#define HDSZ 32
#define ATT_SCALE 0.17677669529663687f
#define ATT_SCALE_LOG2E 0.25506601f   // ATT_SCALE * log2(e)

typedef short short8 __attribute__((ext_vector_type(8)));
typedef short short4v __attribute__((ext_vector_type(4)));
typedef float f32x4 __attribute__((ext_vector_type(4)));
typedef unsigned short ushort;

// wbuf offsets (ushort elements)
#define OFF_PROJ 0
#define OFF_WQ0  393216
#define OFF_WK0  458752
#define OFF_WV0  524288
#define OFF_WO0  589824
#define OFF_W10  655360
#define OFF_W20  917504
#define OFF_WK1  1179648
#define OFF_WV1  1245184
#define OFF_WQ1  1310720
#define OFF_WO1  1376256
#define OFF_W11  1441792
#define OFF_W21  1703936
#define WBUF_TOT 1966080

__device__ inline ushort f2bf(float f) {
    union { float f; unsigned u; } c; c.f = f;
    unsigned u = c.u;
    u += 0x7fffu + ((u >> 16) & 1u);          // RNE
    return (ushort)(u >> 16);
}
__device__ inline float bf2f(ushort u) {
    union { unsigned u; float f; } c; c.u = ((unsigned)u) << 16;
    return c.f;
}
__device__ inline float gelu_exact(float v) {
    return 0.5f * v * (1.0f + erff(v * 0.7071067811865475f));
}
__device__ inline unsigned cvtpk_bf16(float a, float b) {
    unsigned r;
    asm("v_cvt_pk_bf16_f32 %0, %1, %2" : "=v"(r) : "v"(a), "v"(b));
    return r;   // low16 = bf16(a), high16 = bf16(b), RNE
}
__device__ inline short8 cat44(short4v a, short4v b) {
    return __builtin_shufflevector(a, b, 0, 1, 2, 3, 4, 5, 6, 7);
}
__device__ inline float block_sum256(float v, float* red) {
    #pragma unroll
    for (int off = 32; off > 0; off >>= 1) v += __shfl_down(v, off, 64);
    const int wid = threadIdx.x >> 6, lane = threadIdx.x & 63;
    if (lane == 0) red[wid] = v;
    __syncthreads();
    const float s = red[0] + red[1] + red[2] + red[3];
    __syncthreads();
    return s;
}

// ============ setup: weight transposes + bias concat + x->bf16 + cls ============
__global__ __launch_bounds__(256)
void setup_kernel(const float* __restrict__ x, const float* __restrict__ proj_w,
                  const float* __restrict__ Wq, const float* __restrict__ Wk,
                  const float* __restrict__ Wv, const float* __restrict__ Wo,
                  const float* __restrict__ W1, const float* __restrict__ W2,
                  const float* __restrict__ bq, const float* __restrict__ bk,
                  const float* __restrict__ bv, const float* __restrict__ cls_tok,
                  ushort* __restrict__ wbuf, float* __restrict__ bqkv0,
                  float* __restrict__ bkv1, ushort* __restrict__ xbf,
                  float* __restrict__ h)
{
    const int b = blockIdx.x;
    const int t = threadIdx.x;
    if (b >= 482) {
        if (b == 6626) { h[t] = cls_tok[t]; return; }   // cls (tab[0]==0)
        const int i = (b - 482) * 256 + t;
        const int n8 = 8191 * 1536 / 8;
        if (i >= n8) return;
        const float4 a0 = *(const float4*)(x + (size_t)i * 8);
        const float4 a1 = *(const float4*)(x + (size_t)i * 8 + 4);
        ushort tmp[8] = { f2bf(a0.x), f2bf(a0.y), f2bf(a0.z), f2bf(a0.w),
                          f2bf(a1.x), f2bf(a1.y), f2bf(a1.z), f2bf(a1.w) };
        *(uint4*)(xbf + (size_t)i * 8) = *(const uint4*)tmp;
        return;
    }
    if (b >= 480) {
        if (b == 480) {
            for (int i = t; i < 768; i += 256)
                bqkv0[i] = (i < 256) ? bq[i] : ((i < 512) ? bk[i - 256] : bv[i - 512]);
        } else {
            for (int i = t; i < 512; i += 256)
                bkv1[i] = (i < 256) ? bk[256 + i] : bv[i];
        }
        return;
    }
    const float* src; ushort* dst; int R, C, t0;
    if (b < 96)       { src = proj_w;        dst = wbuf + OFF_PROJ; R = 1536; C = 256;  t0 = 0;   }
    else if (b < 112) { src = Wq;            dst = wbuf + OFF_WQ0;  R = 256;  C = 256;  t0 = 96;  }
    else if (b < 128) { src = Wk;            dst = wbuf + OFF_WK0;  R = 256;  C = 256;  t0 = 112; }
    else if (b < 144) { src = Wv;            dst = wbuf + OFF_WV0;  R = 256;  C = 256;  t0 = 128; }
    else if (b < 160) { src = Wo;            dst = wbuf + OFF_WO0;  R = 256;  C = 256;  t0 = 144; }
    else if (b < 224) { src = W1;            dst = wbuf + OFF_W10;  R = 256;  C = 1024; t0 = 160; }
    else if (b < 288) { src = W2;            dst = wbuf + OFF_W20;  R = 1024; C = 256;  t0 = 224; }
    else if (b < 304) { src = Wk + 65536;    dst = wbuf + OFF_WK1;  R = 256;  C = 256;  t0 = 288; }
    else if (b < 320) { src = Wv + 65536;    dst = wbuf + OFF_WV1;  R = 256;  C = 256;  t0 = 304; }
    else if (b < 336) { src = Wq + 65536;    dst = wbuf + OFF_WQ1;  R = 256;  C = 256;  t0 = 320; }
    else if (b < 352) { src = Wo + 65536;    dst = wbuf + OFF_WO1;  R = 256;  C = 256;  t0 = 336; }
    else if (b < 416) { src = W1 + 262144;   dst = wbuf + OFF_W11;  R = 256;  C = 1024; t0 = 352; }
    else              { src = W2 + 262144;   dst = wbuf + OFF_W21;  R = 1024; C = 256;  t0 = 416; }
    const int lt = b - t0;
    const int tC = C >> 6;
    const int tr = lt / tC, tc = lt % tC;
    __shared__ ushort tile[64][68];
    const int col = t & 63;
    const int r4  = t >> 6;
    #pragma unroll
    for (int i = 0; i < 16; ++i) {
        const int row = i * 4 + r4;
        tile[row][col] = f2bf(src[(size_t)(tr * 64 + row) * C + tc * 64 + col]);
    }
    __syncthreads();
    #pragma unroll
    for (int i = 0; i < 16; ++i) {
        const int n = i * 4 + r4;
        dst[(size_t)(tc * 64 + n) * R + tr * 64 + col] = tile[col][n];
    }
}

// ============ LayerNorm over D=256: one ROW PER WAVE, no barriers ============
__global__ __launch_bounds__(256)
void ln_kernel(const float* __restrict__ in, const float* __restrict__ g,
               const float* __restrict__ b, ushort* __restrict__ outp)
{
    const int row  = blockIdx.x * 4 + (threadIdx.x >> 6);
    const int lane = threadIdx.x & 63;
    const float4 xv = *(const float4*)(in + (size_t)row * DD + lane * 4);
    float s = (xv.x + xv.y) + (xv.z + xv.w);
    #pragma unroll
    for (int off = 32; off > 0; off >>= 1) s += __shfl_xor(s, off, 64);
    const float mu = s * (1.0f / 256.0f);
    const float dx = xv.x - mu, dy = xv.y - mu, dz = xv.z - mu, dw = xv.w - mu;
    float v2 = (dx * dx + dy * dy) + (dz * dz + dw * dw);
    #pragma unroll
    for (int off = 32; off > 0; off >>= 1) v2 += __shfl_xor(v2, off, 64);
    const float rs = rsqrtf(v2 * (1.0f / 256.0f) + 1e-5f);
    const float4 gv = *(const float4*)(g + lane * 4);
    const float4 bv = *(const float4*)(b + lane * 4);
    uint2 w;
    w.x = cvtpk_bf16(dx * rs * gv.x + bv.x, dy * rs * gv.y + bv.y);
    w.y = cvtpk_bf16(dz * rs * gv.z + bv.z, dw * rs * gv.w + bv.w);
    *(uint2*)(outp + (size_t)row * DD + lane * 4) = w;
}

// ============ gemm4: BM=64 x BN=64, BK=64, XCD-swizzled 1-D grid ============
// C = [C +] act(A @ Bt^T + bias) [+ pos].  A bf16 MxK, Bt bf16 NxK.
// flags: 1 = acc into fp32 C, 2 = GELU, 4 = bf16 out, 8 = pos-embed,
//        16 = scale cols<256 by ATT_SCALE_LOG2E (pre-scaled Q for attn).
// T3+T4 pipeline: 3 LDS buffers, depth-2 global_load_lds prefetch, counted
// s_waitcnt vmcnt(4) + raw s_barrier, ONE barrier per k-step.
template <int BN>
__global__ __launch_bounds__(256)
void gemm4_kernel(const ushort* __restrict__ A, const ushort* __restrict__ Bt,
                  const float* __restrict__ bias, void* __restrict__ Cv,
                  int M, int N, int K, int flags, const int* __restrict__ coords)
{
    __shared__ ushort As[3][64][64];
    __shared__ ushort Bs[3][BN][64];
    constexpr int NT = BN / 32;                // MFMA n-tiles per wave
    const int nx  = N / BN;
    const int ny8 = gridDim.x / (8 * nx);      // m-slabs per XCD (=16)
    const int b   = blockIdx.x;
    const int c8  = b & 7;
    const int j   = b >> 3;
    const int m0  = (c8 * ny8 + j / nx) * 64;
    const int n0  = (j % nx) * BN;

    const int tid  = threadIdx.x;
    const int wave = tid >> 6;
    const int lane = tid & 63;
    const int lrow = lane & 15;
    const int quad = lane >> 4;
    const int wr = (wave >> 1) * 32;           // {0,32}
    const int wc = (wave & 1) * (BN / 2);      // {0,BN/2}

    float* Cf  = (float*)Cv;
    ushort* Cb = (ushort*)Cv;

    f32x4 acc[2][NT];
    #pragma unroll
    for (int mt = 0; mt < 2; ++mt)
        #pragma unroll
        for (int nt = 0; nt < NT; ++nt)
            acc[mt][nt] = (f32x4){0.f, 0.f, 0.f, 0.f};

    const int srow = tid >> 3;                 // 0..31 row within chunk
    const int scol = (tid & 7) * 16;           // byte col 0..112

    #define STAGE(BUF, KK)                                                        \
    do {                                                                          \
        _Pragma("unroll")                                                         \
        for (int c = 0; c < 2; ++c) {                                             \
            const int row = c * 32 + srow;                                        \
            const int sb  = scol ^ ((row & 7) << 4);                              \
            const ushort* srcp = A + (size_t)(m0 + row) * K + (KK) + (sb >> 1);   \
            __builtin_amdgcn_global_load_lds(                                     \
                (const __attribute__((address_space(1))) void*)srcp,              \
                (__attribute__((address_space(3))) void*)&As[BUF][c * 32 + wave * 8][0], \
                16, 0, 0);                                                        \
        }                                                                         \
        _Pragma("unroll")                                                         \
        for (int c = 0; c < BN / 32; ++c) {                                       \
            const int row = c * 32 + srow;                                        \
            const int sb  = scol ^ ((row & 7) << 4);                              \
            const ushort* srcp = Bt + (size_t)(n0 + row) * K + (KK) + (sb >> 1);  \
            __builtin_amdgcn_global_load_lds(                                     \
                (const __attribute__((address_space(1))) void*)srcp,              \
                (__attribute__((address_space(3))) void*)&Bs[BUF][c * 32 + wave * 8][0], \
                16, 0, 0);                                                        \
        }                                                                         \
    } while (0)

    #define COMPUTE(BUF)                                                          \
    do {                                                                          \
        _Pragma("unroll")                                                         \
        for (int ks = 0; ks < 2; ++ks) {                                          \
            short8 af[2], bfr[NT];                                                \
            _Pragma("unroll")                                                     \
            for (int mt = 0; mt < 2; ++mt) {                                      \
                const int row = wr + mt * 16 + lrow;                              \
                const int cb  = (ks * 64 + quad * 16) ^ ((row & 7) << 4);         \
                af[mt] = *(const short8*)((const char*)&As[BUF][row][0] + cb);    \
            }                                                                     \
            _Pragma("unroll")                                                     \
            for (int nt = 0; nt < NT; ++nt) {                                     \
                const int row = wc + nt * 16 + lrow;                              \
                const int cb  = (ks * 64 + quad * 16) ^ ((row & 7) << 4);         \
                bfr[nt] = *(const short8*)((const char*)&Bs[BUF][row][0] + cb);   \
            }                                                                     \
            _Pragma("unroll")                                                     \
            for (int mt = 0; mt < 2; ++mt)                                        \
                _Pragma("unroll")                                                 \
                for (int nt = 0; nt < NT; ++nt)                                   \
                    acc[mt][nt] = __builtin_amdgcn_mfma_f32_16x16x32_bf16(        \
                                      af[mt], bfr[nt], acc[mt][nt], 0, 0, 0);     \
        }                                                                         \
    } while (0)

    #define WAIT_BAR_N()                                                          \
    do {                                                                          \
        if constexpr (BN == 64) { asm volatile("s_waitcnt vmcnt(4)" ::: "memory"); } \
        else                    { asm volatile("s_waitcnt vmcnt(6)" ::: "memory"); } \
        __builtin_amdgcn_sched_barrier(0);                                        \
        __builtin_amdgcn_s_barrier();                                             \
        __builtin_amdgcn_sched_barrier(0);                                        \
    } while (0)

    #define WAIT_BAR_0()                                                          \
    do {                                                                          \
        asm volatile("s_waitcnt vmcnt(0)" ::: "memory");                          \
        __builtin_amdgcn_sched_barrier(0);                                        \
        __builtin_amdgcn_s_barrier();                                             \
        __builtin_amdgcn_sched_barrier(0);                                        \
    } while (0)

    const int ktiles = K >> 6;                 // >= 4 for all call sites
    STAGE(0, 0);
    STAGE(1, 64);
    int bt = 0;
    for (int t = 0; t < ktiles - 2; ++t) {
        WAIT_BAR_N();                          // tile t landed; t+1 in flight
        const int nb = (bt + 2 >= 3) ? bt - 1 : bt + 2;
        STAGE(nb, (t + 2) * 64);               // in flight: t+1, t+2
        COMPUTE(bt);
        bt = (bt + 1 == 3) ? 0 : bt + 1;
    }
    WAIT_BAR_N();                              // tile ktiles-2 landed
    COMPUTE(bt);
    bt = (bt + 1 == 3) ? 0 : bt + 1;
    WAIT_BAR_0();                              // tile ktiles-1 landed
    COMPUTE(bt);
    #undef STAGE
    #undef COMPUTE
    #undef WAIT_BAR_N
    #undef WAIT_BAR_0

    #pragma unroll
    for (int mt = 0; mt < 2; ++mt) {
        #pragma unroll
        for (int rg = 0; rg < 4; ++rg) {
            const int r = m0 + wr + mt * 16 + quad * 4 + rg;
            if (r >= M) continue;
            #pragma unroll
            for (int nt = 0; nt < NT; ++nt) {
                const int c = n0 + wc + nt * 16 + lrow;
                float vv = acc[mt][nt][rg] + bias[c];
                if (flags & 8) {   // pos-embed for token r (output = h row r+1)
                    const int cg = coords[2 * r + ((c < 128) ? 1 : 0)] >> 8;
                    // omega = 10000^(-(c&63)/64) = exp2(-(c&63)*log2(1e4)/64)
                    const float omega = exp2f((float)(c & 63) * -0.2076205059304703f);
                    const float o = (float)cg * omega;
                    vv += ((c & 64) == 0) ? __sinf(o) : __cosf(o);
                }
                if (flags & 16) { if (c < 256) vv *= ATT_SCALE_LOG2E; }
                if (flags & 2) vv = gelu_exact(vv);
                if (flags & 4) {
                    Cb[(size_t)r * N + c] = f2bf(vv);
                } else {
                    if (flags & 1) vv += Cf[(size_t)r * N + c];
                    Cf[(size_t)r * N + c] = vv;
                }
            }
        }
    }
}

// ============ MFMA dilated attention (bf16, no-max softmax) ============
// R7/R10-verified version (59.5us): 4 waves/block, swapped QK^T, register-
// resident P, rotated Vt, double-buffered Kb/Vt, 1-step register prefetch.
__global__ __launch_bounds__(256)
void attn_mfma_kernel(const ushort* __restrict__ q, const ushort* __restrict__ k,
                      const ushort* __restrict__ v, float* __restrict__ bo5,
                      float* __restrict__ lse5, int qs)
{
    __shared__ ushort Kb[2][64][40];
    __shared__ ushort Vt[2][32][72];

    const int unit = blockIdx.x;
    const int segu = unit >> 3;
    const int head = unit & 7;
    int b2, n;
    if (segu < 8)        { b2 = 0; n = segu; }
    else if (segu < 12)  { b2 = 1; n = segu - 8; }
    else if (segu < 14)  { b2 = 2; n = segu - 12; }
    else if (segu == 14) { b2 = 3; n = 0; }
    else                 { b2 = 4; n = 0; }
    const int w  = 1024 << b2;
    const int rr = 1 << b2;
    const int base = n * w + (head & (rr - 1));

    int kEnd = (S_TOT - base + rr - 1) >> b2;
    if (kEnd > 1024) kEnd = 1024;
    if (blockIdx.y * 128 >= kEnd) return;

    const int tid  = threadIdx.x;
    const int wave = tid >> 6;
    const int lane = tid & 63;
    const int lrow = lane & 15;
    const int quad = lane >> 4;

    short8 qf[2];
    #pragma unroll
    for (int m = 0; m < 2; ++m) {
        const int j  = blockIdx.y * 128 + wave * 32 + m * 16 + lrow;
        const int pq = base + rr * j;
        qf[m] = *(const short8*)(q + (size_t)pq * qs + head * HDSZ + quad * 8);
    }

    f32x4 acc[2][2];
    float lsum[2] = {0.f, 0.f};        // per-lane partial, q = lrow
    #pragma unroll
    for (int m = 0; m < 2; ++m)
        #pragma unroll
        for (int dt = 0; dt < 2; ++dt) acc[m][dt] = (f32x4){0.f, 0.f, 0.f, 0.f};

    const int skr = tid >> 2;          // 0..63 (k row staged by this thread)
    const int sdb = (tid & 3) * 8;     // 0,8,16,24 (d offset staged)
    const int grp = tid & 3;           // = sdb>>3
    const int wcol = (2 * skr + 32 * grp) & 127;   // rotated byte col for V^T write

    // load step 0
    size_t prow = (size_t)(base + rr * skr) * qs + head * HDSZ + sdb;
    uint4 kreg = *(const uint4*)(k + prow);
    uint4 vreg = *(const uint4*)(v + prow);

    // stage step 0 into buf 0
    *(uint4*)&Kb[0][skr][sdb] = kreg;
    {
        const ushort* vp = (const ushort*)&vreg;
        #pragma unroll
        for (int i = 0; i < 8; ++i)
            *(ushort*)((char*)&Vt[0][sdb + i][0] + wcol) = vp[i];
    }

    int cur = 0;
    for (int kc = 0; kc < kEnd; kc += 64) {
        __syncthreads();               // buf[cur] ready for all waves
        const bool more = (kc + 64 < kEnd);
        if (more) {                    // prefetch next step (global)
            prow = (size_t)(base + rr * (kc + 64 + skr)) * qs + head * HDSZ + sdb;
            kreg = *(const uint4*)(k + prow);
            vreg = *(const uint4*)(v + prow);
        }

        short8 kf[4];
        #pragma unroll
        for (int t = 0; t < 4; ++t)
            kf[t] = *(const short8*)&Kb[cur][t * 16 + lrow][quad * 8];

        short8 vf[2][2];
        #pragma unroll
        for (int g = 0; g < 2; ++g)
            #pragma unroll
            for (int dt = 0; dt < 2; ++dt) {
                const int row  = dt * 16 + lrow;
                const int rotb = 32 * ((row >> 3) & 3);
                const int cb0  = (64 * g + 8 * quad + rotb) & 127;
                const int cb1  = (64 * g + 8 * quad + 32 + rotb) & 127;
                vf[g][dt] = cat44(*(const short4v*)((const char*)&Vt[cur][row][0] + cb0),
                                  *(const short4v*)((const char*)&Vt[cur][row][0] + cb1));
            }

        #pragma unroll
        for (int m = 0; m < 2; ++m) {
            f32x4 sc[4];
            #pragma unroll
            for (int t = 0; t < 4; ++t)       // SWAPPED: P^T fragments
                sc[t] = __builtin_amdgcn_mfma_f32_16x16x32_bf16(
                            kf[t], qf[m], (f32x4){0.f,0.f,0.f,0.f}, 0, 0, 0);
            float p[4][4];
            #pragma unroll
            for (int t = 0; t < 4; ++t)
                #pragma unroll
                for (int rg = 0; rg < 4; ++rg)
                    p[t][rg] = exp2f(sc[t][rg]);     // Q pre-scaled in gemm
            float ps = 0.f;
            #pragma unroll
            for (int t = 0; t < 4; ++t)
                ps += (p[t][0] + p[t][1]) + (p[t][2] + p[t][3]);
            lsum[m] += ps;
            unsigned pw[4][2];
            #pragma unroll
            for (int t = 0; t < 4; ++t) {
                pw[t][0] = cvtpk_bf16(p[t][0], p[t][1]);
                pw[t][1] = cvtpk_bf16(p[t][2], p[t][3]);
            }
            #pragma unroll
            for (int g = 0; g < 2; ++g) {
                union { short8 s; unsigned u[4]; } pa;
                pa.u[0] = pw[2 * g][0];
                pa.u[1] = pw[2 * g][1];
                pa.u[2] = pw[2 * g + 1][0];
                pa.u[3] = pw[2 * g + 1][1];
                #pragma unroll
                for (int dt = 0; dt < 2; ++dt)
                    acc[m][dt] = __builtin_amdgcn_mfma_f32_16x16x32_bf16(
                                     pa.s, vf[g][dt], acc[m][dt], 0, 0, 0);
            }
        }

        if (more) {                    // stage next step into the other buffer
            *(uint4*)&Kb[cur ^ 1][skr][sdb] = kreg;
            const ushort* vp = (const ushort*)&vreg;
            #pragma unroll
            for (int i = 0; i < 8; ++i)
                *(ushort*)((char*)&Vt[cur ^ 1][sdb + i][0] + wcol) = vp[i];
        }
        cur ^= 1;
    }

    #pragma unroll
    for (int m = 0; m < 2; ++m) {
        float tot = lsum[m];
        tot += __shfl_xor(tot, 16, 64);
        tot += __shfl_xor(tot, 32, 64);    // all quads now hold sum for q=lrow
        #pragma unroll
        for (int rg = 0; rg < 4; ++rg) {
            const float li = __shfl(tot, quad * 4 + rg, 16);  // sum for q=quad*4+rg
            const int j  = blockIdx.y * 128 + wave * 32 + m * 16 + quad * 4 + rg;
            const int pq = base + rr * j;
            const float inv = 1.0f / li;
            float* dst = bo5 + ((size_t)b2 * S_TOT + pq) * DD + head * HDSZ;
            dst[lrow]      = acc[m][0][rg] * inv;
            dst[16 + lrow] = acc[m][1][rg] * inv;
            if (lrow == 0)
                lse5[((size_t)b2 * S_TOT + pq) * NHEAD + head] = __logf(li);
        }
    }
}

// ============ layer-1 pruned attention: query position 0 only ============
__global__ __launch_bounds__(64)
void attn_row0_kernel(const float* __restrict__ q, const ushort* __restrict__ k,
                      const ushort* __restrict__ v, float* __restrict__ bo5,
                      float* __restrict__ lse5, int kvs)
{
    const int b2 = blockIdx.x >> 3;
    const int head = blockIdx.x & 7;
    const int r = 1 << b2;
    if (head & (r - 1)) return;
    const int tid = threadIdx.x;
    float qreg[32];
    #pragma unroll
    for (int d = 0; d < 32; d += 4) {
        const float4 t4 = *(const float4*)(q + head * HDSZ + d);
        qreg[d] = t4.x; qreg[d+1] = t4.y; qreg[d+2] = t4.z; qreg[d+3] = t4.w;
    }
    float m = -3.0e38f, l = 0.f, o[32];
    #pragma unroll
    for (int d = 0; d < 32; ++d) o[d] = 0.f;
    for (int j = tid; j < 1024; j += 64) {
        const int pk = r * j;
        float s;
        if (pk < S_TOT) {
            float s0 = 0.f;
            #pragma unroll
            for (int d = 0; d < 32; d += 8) {
                const uint4 raw = *(const uint4*)(k + (size_t)pk * kvs + head * HDSZ + d);
                const ushort* kp = (const ushort*)&raw;
                #pragma unroll
                for (int i = 0; i < 8; ++i) s0 += qreg[d + i] * bf2f(kp[i]);
            }
            s = s0 * ATT_SCALE;
        } else s = -1.0e9f;
        const float mn = fmaxf(m, s);
        const float c = __expf(m - mn);
        const float e = __expf(s - mn);
        l = l * c + e; m = mn;
        if (pk < S_TOT) {
            #pragma unroll
            for (int d = 0; d < 32; d += 8) {
                const uint4 raw = *(const uint4*)(v + (size_t)pk * kvs + head * HDSZ + d);
                const ushort* vp = (const ushort*)&raw;
                #pragma unroll
                for (int i = 0; i < 8; ++i) o[d + i] = o[d + i] * c + e * bf2f(vp[i]);
            }
        } else {
            #pragma unroll
            for (int d = 0; d < 32; ++d) o[d] *= c;
        }
    }
    __shared__ float ms[64], ls[64], os[64][32];
    ms[tid] = m; ls[tid] = l;
    #pragma unroll
    for (int d = 0; d < 32; ++d) os[tid][d] = o[d];
    __syncthreads();
    for (int st = 32; st >= 1; st >>= 1) {
        if (tid < st) {
            const float m2 = ms[tid + st], l2 = ls[tid + st];
            const float mn = fmaxf(ms[tid], m2);
            const float c1 = __expf(ms[tid] - mn);
            const float c2 = __expf(m2 - mn);
            ls[tid] = ls[tid] * c1 + l2 * c2;
            ms[tid] = mn;
            for (int d = 0; d < 32; ++d) os[tid][d] = os[tid][d]*c1 + os[tid+st][d]*c2;
        }
        __syncthreads();
    }
    if (tid < 32) bo5[(size_t)b2 * S_TOT * DD + head * HDSZ + tid] = os[0][tid] / ls[0];
    if (tid == 0) lse5[(size_t)b2 * S_TOT * NHEAD + head] = ms[0] + __logf(ls[0]);
}

// ============ combine 5 branches (layer 0), bf16 out ============
__global__ __launch_bounds__(256)
void combine_kernel(const float* __restrict__ bo5, const float* __restrict__ lse5,
                    ushort* __restrict__ attn)
{
    const int p = blockIdx.x;
    const int d = threadIdx.x;
    const int h = d >> 5;
    float lse[5];
    bool sel[5];
    float mx = -3.0e38f;
    #pragma unroll
    for (int b2 = 0; b2 < 5; ++b2) {
        const int r = 1 << b2;
        sel[b2] = ((p & (r - 1)) == (h & (r - 1)));
        if (sel[b2]) {
            lse[b2] = lse5[((size_t)b2 * S_TOT + p) * NHEAD + h];
            mx = fmaxf(mx, lse[b2]);
        }
    }
    float wsum = 0.f, acc = 0.f;
    #pragma unroll
    for (int b2 = 0; b2 < 5; ++b2) {
        if (sel[b2]) {
            const float wgt = __expf(lse[b2] - mx);
            wsum += wgt;
            acc += wgt * bo5[((size_t)b2 * S_TOT + p) * DD + d];
        }
    }
    attn[(size_t)p * DD + d] = f2bf(acc / wsum);
}

// ============ tail kernels (row 0 only), PARALLELIZED over 16 blocks each ====
// v2: each 1-block gemv was latency-bound (one CU fetching 128-512KB of
// weights). Now each kernel runs 16 blocks; the cheap shared prefix (LN of a
// 256-elem row / combine-att) is recomputed redundantly per block; each block
// owns a disjoint slice of outputs with the dot split across 4-16 lanes.
__global__ __launch_bounds__(256)
void tail_qrow_kernel(const float* __restrict__ h, const float* __restrict__ g,
                      const float* __restrict__ b, const ushort* __restrict__ Wt,
                      const float* __restrict__ bias, float* __restrict__ qrow0)
{
    __shared__ float red[4];
    __shared__ float as[256];
    const int tid = threadIdx.x;
    const float xv = h[tid];
    const float mu = block_sum256(xv, red) * (1.0f / 256.0f);
    const float dv = xv - mu;
    const float var = block_sum256(dv * dv, red) * (1.0f / 256.0f);
    as[tid] = dv * rsqrtf(var + 1e-5f) * g[tid] + b[tid];
    __syncthreads();
    const int n  = blockIdx.x * 16 + (tid >> 4);   // 16 outputs/block
    const int k0 = (tid & 15) * 16;                // 16 k-elems/lane
    float acc = 0.f;
    #pragma unroll
    for (int k2 = 0; k2 < 16; k2 += 8) {
        const short8 w8 = *(const short8*)&Wt[(size_t)n * 256 + k0 + k2];
        #pragma unroll
        for (int j = 0; j < 8; ++j) acc += as[k0 + k2 + j] * bf2f((ushort)w8[j]);
    }
    #pragma unroll
    for (int off = 8; off >= 1; off >>= 1) acc += __shfl_xor(acc, off, 16);
    if ((tid & 15) == 0) qrow0[n] = acc + bias[n];
}

__global__ __launch_bounds__(256)
void tail_mid_kernel(const float* __restrict__ bo5, const float* __restrict__ lse5,
                     float* __restrict__ h, const ushort* __restrict__ Wo1t,
                     const float* __restrict__ bo1)
{
    __shared__ float att[256];
    const int tid = threadIdx.x;
    const int hh = tid >> 5;
    float lse[5]; bool sel[5]; float mx = -3.0e38f;
    #pragma unroll
    for (int bb = 0; bb < 5; ++bb) {
        const int r = 1 << bb;
        sel[bb] = ((hh & (r - 1)) == 0);
        if (sel[bb]) {
            lse[bb] = lse5[(size_t)bb * S_TOT * NHEAD + hh];
            mx = fmaxf(mx, lse[bb]);
        }
    }
    float wsum = 0.f, acc0 = 0.f;
    #pragma unroll
    for (int bb = 0; bb < 5; ++bb) {
        if (sel[bb]) {
            const float wgt = __expf(lse[bb] - mx);
            wsum += wgt;
            acc0 += wgt * bo5[(size_t)bb * S_TOT * DD + tid];
        }
    }
    att[tid] = acc0 / wsum;
    __syncthreads();
    const int n  = blockIdx.x * 16 + (tid >> 4);
    const int k0 = (tid & 15) * 16;
    float a2 = 0.f;
    #pragma unroll
    for (int k2 = 0; k2 < 16; k2 += 8) {
        const short8 w8 = *(const short8*)&Wo1t[(size_t)n * 256 + k0 + k2];
        #pragma unroll
        for (int j = 0; j < 8; ++j) a2 += att[k0 + k2 + j] * bf2f((ushort)w8[j]);
    }
    #pragma unroll
    for (int off = 8; off >= 1; off >>= 1) a2 += __shfl_xor(a2, off, 16);
    if ((tid & 15) == 0) h[n] = a2 + bo1[n] + h[n];   // each n owned by one lane
}

__global__ __launch_bounds__(256)
void tail_ffn1_kernel(const float* __restrict__ h, const float* __restrict__ g2,
                      const float* __restrict__ b2l, const ushort* __restrict__ W11t,
                      const float* __restrict__ b11, float* __restrict__ midr0)
{
    __shared__ float red[4];
    __shared__ float fs[256];
    const int tid = threadIdx.x;
    const float xv = h[tid];                       // post-mid h row0
    const float mu = block_sum256(xv, red) * (1.0f / 256.0f);
    const float dv = xv - mu;
    const float var = block_sum256(dv * dv, red) * (1.0f / 256.0f);
    fs[tid] = dv * rsqrtf(var + 1e-5f) * g2[tid] + b2l[tid];
    __syncthreads();
    const int n  = blockIdx.x * 64 + (tid >> 2);   // 64 outputs/block
    const int k0 = (tid & 3) * 64;                 // 64 k-elems/lane
    float acc = 0.f;
    for (int k2 = 0; k2 < 64; k2 += 8) {
        const short8 w8 = *(const short8*)&W11t[(size_t)n * 256 + k0 + k2];
        #pragma unroll
        for (int j = 0; j < 8; ++j) acc += fs[k0 + k2 + j] * bf2f((ushort)w8[j]);
    }
    acc += __shfl_xor(acc, 1, 4);
    acc += __shfl_xor(acc, 2, 4);
    if ((tid & 3) == 0) midr0[n] = gelu_exact(acc + b11[n]);
}

__global__ __launch_bounds__(256)
void tail_ffn2_kernel(const float* __restrict__ midr0, const ushort* __restrict__ W21t,
                      const float* __restrict__ b21, float* __restrict__ h)
{
    __shared__ float ms[1024];
    const int tid = threadIdx.x;
    for (int i = tid; i < 1024; i += 256) ms[i] = midr0[i];
    __syncthreads();
    const int n  = blockIdx.x * 16 + (tid >> 4);   // 16 outputs/block
    const int k0 = (tid & 15) * 64;                // 64 k-elems/lane
    float acc = 0.f;
    for (int k2 = 0; k2 < 64; k2 += 8) {
        const short8 w8 = *(const short8*)&W21t[(size_t)n * 1024 + k0 + k2];
        #pragma unroll
        for (int j = 0; j < 8; ++j) acc += ms[k0 + k2 + j] * bf2f((ushort)w8[j]);
    }
    #pragma unroll
    for (int off = 8; off >= 1; off >>= 1) acc += __shfl_xor(acc, off, 16);
    if ((tid & 15) == 0) h[n] = h[n] + acc + b21[n];
}

__global__ __launch_bounds__(256)
void tail_final_kernel(const float* __restrict__ h, const float* __restrict__ eg,
                       const float* __restrict__ eb, const float* __restrict__ ng,
                       const float* __restrict__ nb, float* __restrict__ out)
{
    __shared__ float red[4];
    const int d = threadIdx.x;
    float xv = h[d];
    {
        const float mu = block_sum256(xv, red) * (1.0f / 256.0f);
        const float dv = xv - mu;
        const float var = block_sum256(dv * dv, red) * (1.0f / 256.0f);
        xv = dv * rsqrtf(var + 1e-5f) * eg[d] + eb[d];
    }
    {
        const float mu = block_sum256(xv, red) * (1.0f / 256.0f);
        const float dv = xv - mu;
        const float var = block_sum256(dv * dv, red) * (1.0f / 256.0f);
        out[d] = dv * rsqrtf(var + 1e-5f) * ng[d] + nb[d];
    }
}

extern "C" void kernel_launch(void* const* d_in, const int* in_sizes, int n_in,
                              void* d_out, int out_size, void* d_ws, size_t ws_size,
                              hipStream_t stream)
{
    const float* x      = (const float*)d_in[0];
    const int*   coords = (const int*)  d_in[1];
    const float* proj_w = (const float*)d_in[2];
    const float* proj_b = (const float*)d_in[3];
    const float* cls_tok= (const float*)d_in[4];
    const float* Wq     = (const float*)d_in[5];
    const float* Wk     = (const float*)d_in[6];
    const float* Wv     = (const float*)d_in[7];
    const float* Wo     = (const float*)d_in[8];
    const float* bq     = (const float*)d_in[9];
    const float* bk     = (const float*)d_in[10];
    const float* bv     = (const float*)d_in[11];
    const float* bo_    = (const float*)d_in[12];
    const float* ln1_g  = (const float*)d_in[13];
    const float* ln1_b  = (const float*)d_in[14];
    const float* ln2_g  = (const float*)d_in[15];
    const float* ln2_b  = (const float*)d_in[16];
    const float* W1     = (const float*)d_in[17];
    const float* b1     = (const float*)d_in[18];
    const float* W2     = (const float*)d_in[19];
    const float* b2v    = (const float*)d_in[20];
    const float* enc_g  = (const float*)d_in[21];
    const float* enc_b  = (const float*)d_in[22];
    const float* norm_g = (const float*)d_in[23];
    const float* norm_b = (const float*)d_in[24];
    float* out = (float*)d_out;

    const size_t SD = (size_t)S_TOT * DD;      // 2,097,152
    float* ws   = (float*)d_ws;
    float* h    = ws;                          // SD fp32
    float* big  = h + SD;                      // 5*SD fp32: bo5 | xbf | midbf overlay
    float* bo5  = big;
    ushort* xbf   = (ushort*)big;              // 8191*1536 ushort
    ushort* midbf = (ushort*)big;              // 8192*1024 ushort
    float* lse5 = big + 5 * SD;                // 327,680 fp32
    ushort* a_bf    = (ushort*)(lse5 + 5 * S_TOT * NHEAD);   // SD ushort
    ushort* qkv_bf  = a_bf + SD;               // 3*SD ushort
    ushort* attn_bf = qkv_bf + 3 * SD;         // SD ushort
    ushort* wbuf    = attn_bf + SD;            // WBUF_TOT ushort
    float* bqkv0  = (float*)(wbuf + WBUF_TOT); // 768
    float* bkv1   = bqkv0 + 768;               // 512
    float* qrow0  = bkv1 + 512;                // 256
    float* midr0  = qrow0 + 256;               // 1024

    auto gemm64 = [&](const ushort* A, const ushort* Bt, const float* bias, void* C,
                      int M, int N, int K, int flags) {
        gemm4_kernel<64><<<128 * (N / 64), 256, 0, stream>>>(A, Bt, bias, C, M, N, K,
                                                             flags, coords);
    };

    // ---- setup ----
    setup_kernel<<<6627, 256, 0, stream>>>(x, proj_w, Wq, Wk, Wv, Wo, W1, W2,
                                           bq, bk, bv, cls_tok, wbuf, bqkv0, bkv1,
                                           xbf, h);

    // ---- projection (+ fused pos-embed) ----
    gemm64(xbf, wbuf + OFF_PROJ, proj_b, h + DD, 8191, 256, 1536, 8);

    // ---- layer 0 ----
    ln_kernel<<<S_TOT / 4, 256, 0, stream>>>(h, ln1_g, ln1_b, a_bf);
    gemm64(a_bf, wbuf + OFF_WQ0, bqkv0, qkv_bf, 8192, 768, 256, 4 | 16); // QKV, Q pre-scaled
    attn_mfma_kernel<<<dim3(128, 8), 256, 0, stream>>>(qkv_bf, qkv_bf + 256,
                                                       qkv_bf + 512, bo5, lse5, 768);
    combine_kernel<<<S_TOT, 256, 0, stream>>>(bo5, lse5, attn_bf);
    gemm64(attn_bf, wbuf + OFF_WO0, bo_, h, 8192, 256, 256, 1);          // Wo, acc
    ln_kernel<<<S_TOT / 4, 256, 0, stream>>>(h, ln2_g, ln2_b, a_bf);
    gemm64(a_bf, wbuf + OFF_W10, b1, midbf, 8192, 1024, 256, 4 | 2);     // FFN1 gelu
    gemm64(midbf, wbuf + OFF_W20, b2v, h, 8192, 256, 1024, 1);           // FFN2, acc

    // ---- layer 1 (pruned) ----
    ln_kernel<<<S_TOT / 4, 256, 0, stream>>>(h, ln1_g + 256, ln1_b + 256, a_bf);
    gemm64(a_bf, wbuf + OFF_WK1, bkv1, qkv_bf, 8192, 512, 256, 4);       // K,V
    tail_qrow_kernel<<<16, 256, 0, stream>>>(h, ln1_g + 256, ln1_b + 256,
                                             wbuf + OFF_WQ1, bq + 256, qrow0);
    attn_row0_kernel<<<40, 64, 0, stream>>>(qrow0, qkv_bf, qkv_bf + 256, bo5, lse5, 512);
    tail_mid_kernel<<<16, 256, 0, stream>>>(bo5, lse5, h, wbuf + OFF_WO1, bo_ + 256);
    tail_ffn1_kernel<<<16, 256, 0, stream>>>(h, ln2_g + 256, ln2_b + 256,
                                             wbuf + OFF_W11, b1 + 1024, midr0);
    tail_ffn2_kernel<<<16, 256, 0, stream>>>(midr0, wbuf + OFF_W21, b2v + 256, h);
    tail_final_kernel<<<1, 256, 0, stream>>>(h, enc_g, enc_b, norm_g, norm_b, out);
}